// Round 7
// baseline (309.046 us; speedup 1.0000x reference)
//
#include <hip/hip_runtime.h>

#define NF 128
#define NBSHIFT 8        // 256 nodes per bucket
#define NBMAX 512        // padded bucket count for scans
#define CHUNK 4096       // edges per multisplit chunk

typedef __attribute__((ext_vector_type(8))) short bf16x8;
typedef __attribute__((ext_vector_type(4))) float f32x4;

__device__ __forceinline__ unsigned short f2bf(float f) {
    unsigned int u = __builtin_bit_cast(unsigned int, f);
    u = (u + 0x7fffu + ((u >> 16) & 1u)) >> 16;
    return (unsigned short)u;
}
__device__ __forceinline__ float bflo(unsigned int u) {
    return __builtin_bit_cast(float, u << 16);
}
__device__ __forceinline__ float bfhi(unsigned int u) {
    return __builtin_bit_cast(float, u & 0xffff0000u);
}

// ================= fused prep: bhist | buildBt | cvt =================
// blocks [0,256): dst-bucket histogram; [256,512): weight transpose+cvt;
// [512, 512+cvtBlocks): x -> bf16.
#define BH 256
#define BT 256
__global__ __launch_bounds__(256) void k_prep(const int* __restrict__ dst, int E, int NB,
                                              int* __restrict__ gbhist,
                                              const float* __restrict__ x,
                                              unsigned short* __restrict__ xb,
                                              const float* __restrict__ Win,
                                              const float* __restrict__ Wout,
                                              unsigned short* __restrict__ BtIn,
                                              unsigned short* __restrict__ BtOut) {
    __shared__ int lh[NBMAX];
    const int bb = blockIdx.x;
    const int t = threadIdx.x;
    if (bb < BH) {
        for (int k = t; k < NBMAX; k += 256) lh[k] = 0;
        __syncthreads();
        for (int i = bb * 256 + t; i < E; i += BH * 256)
            atomicAdd(&lh[((unsigned)dst[i]) >> NBSHIFT], 1);
        __syncthreads();
        for (int k = t; k < NB; k += 256)
            if (lh[k]) atomicAdd(&gbhist[k], lh[k]);
    } else if (bb < BH + BT) {
        int b2 = bb - BH;
        const float* W = (b2 < 128) ? Win : Wout;
        unsigned short* Bt = (b2 < 128) ? BtIn : BtOut;
        int idx = (b2 & 127) * 256 + t;
        int c = idx >> 8;
        int k = idx & 255;
        int p = k >> 7, kk = k & 127;
        Bt[idx] = f2bf(W[((size_t)p * NF + kk) * NF + c]);
    } else {
        long long i = (long long)(bb - BH - BT) * 256 + t;
        const float4 a = *reinterpret_cast<const float4*>(x + i * 8);
        const float4 b = *reinterpret_cast<const float4*>(x + i * 8 + 4);
        union { unsigned short s[8]; uint4 u; } o;
        o.s[0] = f2bf(a.x); o.s[1] = f2bf(a.y); o.s[2] = f2bf(a.z); o.s[3] = f2bf(a.w);
        o.s[4] = f2bf(b.x); o.s[5] = f2bf(b.y); o.s[6] = f2bf(b.z); o.s[7] = f2bf(b.w);
        *reinterpret_cast<uint4*>(xb + i * 8) = o.u;
    }
}

// ================= CSR build =================

__global__ __launch_bounds__(256) void k_bscan(const int* __restrict__ gbhist,
                                               int* __restrict__ bbase, int* __restrict__ gcursor,
                                               int NB, int E, int* __restrict__ offsets, int n) {
    __shared__ int sA[NBMAX], sB[NBMAX];
    int t = threadIdx.x;
    for (int k = t; k < NBMAX; k += 256) sA[k] = (k < NB) ? gbhist[k] : 0;
    __syncthreads();
    int* pin = sA;
    int* pout = sB;
    for (int off = 1; off < NBMAX; off <<= 1) {
        for (int k = t; k < NBMAX; k += 256) pout[k] = pin[k] + (k >= off ? pin[k - off] : 0);
        __syncthreads();
        int* tmp = pin; pin = pout; pout = tmp;
    }
    for (int k = t; k < NB; k += 256) {
        int excl = pin[k] - gbhist[k];
        bbase[k] = excl;
        gcursor[k] = excl;
    }
    if (t == 0) {
        bbase[NB] = E;
        offsets[n] = E;
    }
}

// chunked multisplit; edge packed 32-bit: (dst&255)<<24 | src  (needs n < 2^24)
__global__ __launch_bounds__(256) void k_bucket(const int* __restrict__ src,
                                                const int* __restrict__ dst,
                                                int* __restrict__ gcursor,
                                                unsigned* __restrict__ gpairs, int E) {
    __shared__ int lhist[NBMAX], lbase[NBMAX], lcur[NBMAX], gb[NBMAX];
    __shared__ int sA[NBMAX], sB[NBMAX];
    __shared__ unsigned stage[CHUNK];
    __shared__ unsigned short stage_b[CHUNK];
    const int t = threadIdx.x;
    const int c0 = blockIdx.x * CHUNK;
    const int cc = min(CHUNK, E - c0);

    for (int k = t; k < NBMAX; k += 256) lhist[k] = 0;
    __syncthreads();

    int ls[16], ld[16];
#pragma unroll
    for (int j = 0; j < 16; ++j) {
        int i = t + j * 256;
        ls[j] = 0; ld[j] = 0;
        if (i < cc) {
            ls[j] = src[c0 + i];
            ld[j] = dst[c0 + i];
            atomicAdd(&lhist[((unsigned)ld[j]) >> NBSHIFT], 1);
        }
    }
    __syncthreads();
    for (int k = t; k < NBMAX; k += 256) sA[k] = lhist[k];
    __syncthreads();
    int* pin = sA;
    int* pout = sB;
    for (int off = 1; off < NBMAX; off <<= 1) {
        for (int k = t; k < NBMAX; k += 256) pout[k] = pin[k] + (k >= off ? pin[k - off] : 0);
        __syncthreads();
        int* tmp = pin; pin = pout; pout = tmp;
    }
    for (int k = t; k < NBMAX; k += 256) {
        int excl = pin[k] - lhist[k];
        lbase[k] = excl;
        lcur[k] = excl;
        int cnt = lhist[k];
        if (cnt > 0) gb[k] = atomicAdd(&gcursor[k], cnt);
    }
    __syncthreads();
#pragma unroll
    for (int j = 0; j < 16; ++j) {
        int i = t + j * 256;
        if (i < cc) {
            int b = ((unsigned)ld[j]) >> NBSHIFT;
            int pos = atomicAdd(&lcur[b], 1);
            stage[pos] = (((unsigned)ld[j] & 255u) << 24) | (unsigned)ls[j];
            stage_b[pos] = (unsigned short)b;
        }
    }
    __syncthreads();
    for (int idx = t; idx < cc; idx += 256) {
        unsigned p = stage[idx];
        int b = stage_b[idx];
        gpairs[gb[b] + (idx - lbase[b])] = p;
    }
}

// per-bucket: per-node hist + scan -> offsets/invdeg, scatter esrc within bucket region
__global__ __launch_bounds__(256) void k_bsort(const unsigned* __restrict__ gpairs,
                                               const int* __restrict__ bbase,
                                               int* __restrict__ offsets,
                                               float* __restrict__ invdeg,
                                               int* __restrict__ esrc, int n) {
    __shared__ int lcnt[256], lcur[256], sA[256], sB[256];
    const int b = blockIdx.x;
    const int t = threadIdx.x;
    const int base = bbase[b];
    const int c = bbase[b + 1] - base;
    const int n0 = b << NBSHIFT;

    lcnt[t] = 0;
    __syncthreads();
    for (int i = t; i < c; i += 256) {
        int node = (int)(gpairs[base + i] >> 24);
        atomicAdd(&lcnt[node], 1);
    }
    __syncthreads();
    sA[t] = lcnt[t];
    __syncthreads();
    int* pin = sA;
    int* pout = sB;
    for (int off = 1; off < 256; off <<= 1) {
        pout[t] = pin[t] + (t >= off ? pin[t - off] : 0);
        __syncthreads();
        int* tmp = pin; pin = pout; pout = tmp;
    }
    int excl = pin[t] - lcnt[t];
    lcur[t] = excl;
    int node_g = n0 + t;
    if (node_g < n) {
        offsets[node_g] = base + excl;
        invdeg[node_g] = 1.0f / (float)max(lcnt[t], 1);
    }
    __syncthreads();
    for (int i = t; i < c; i += 256) {
        unsigned p = gpairs[base + i];
        int node = (int)(p >> 24);
        int pos = atomicAdd(&lcur[node], 1);
        esrc[base + pos] = (int)(p & 0x00ffffffu);
    }
}

// ================= gather aggregation (bf16, column-half pass) =================
// One wave per dst node; lane = (g = lane>>3: 8 edge slots, q = lane&7: 16B col group).
// Each launch covers 128 bytes (half the row): pass 0 = bytes [0,128), pass 1 = [128,256).
// Whole-GPU pass split halves the gather working set (25.6 -> 12.8 MB) for L2 locality.
__global__ __launch_bounds__(256) void k_agg_half(const unsigned short* __restrict__ feat,
                                                  const int* __restrict__ esrc,
                                                  const int* __restrict__ offsets,
                                                  const float* __restrict__ invdeg,
                                                  unsigned short* __restrict__ neigh,
                                                  int n, int pass) {
    int wid0 = (int)(((long long)blockIdx.x * blockDim.x + threadIdx.x) >> 6);
    const int wid = __builtin_amdgcn_readfirstlane(wid0);
    if (wid >= n) return;
    const int lane = threadIdx.x & 63;
    const int g = lane >> 3;        // edge slot (8)
    const int q = lane & 7;         // column group (8 x 16B = 128B)
    const unsigned qoff = (unsigned)q * 16u + (unsigned)pass * 128u;
    const char* fb = (const char*)feat;

    const int beg = offsets[wid];
    const int end = offsets[wid + 1];
    float a0 = 0.f, a1 = 0.f, a2 = 0.f, a3 = 0.f, a4 = 0.f, a5 = 0.f, a6 = 0.f, a7 = 0.f;

    int i = beg;
    for (; i + 16 <= end; i += 16) {
        int ea = esrc[i + g];
        int eb = esrc[i + 8 + g];
        uint4 va = *(const uint4*)(fb + (unsigned)ea * 256u + qoff);
        uint4 vb = *(const uint4*)(fb + (unsigned)eb * 256u + qoff);
        a0 += bflo(va.x); a1 += bfhi(va.x); a2 += bflo(va.y); a3 += bfhi(va.y);
        a4 += bflo(va.z); a5 += bfhi(va.z); a6 += bflo(va.w); a7 += bfhi(va.w);
        a0 += bflo(vb.x); a1 += bfhi(vb.x); a2 += bflo(vb.y); a3 += bfhi(vb.y);
        a4 += bflo(vb.z); a5 += bfhi(vb.z); a6 += bflo(vb.w); a7 += bfhi(vb.w);
    }
    for (; i + 8 <= end; i += 8) {
        int ea = esrc[i + g];
        uint4 va = *(const uint4*)(fb + (unsigned)ea * 256u + qoff);
        a0 += bflo(va.x); a1 += bfhi(va.x); a2 += bflo(va.y); a3 += bfhi(va.y);
        a4 += bflo(va.z); a5 += bfhi(va.z); a6 += bflo(va.w); a7 += bfhi(va.w);
    }
    {
        int r = end - i;  // 0..7
        if (g < r) {
            int ea = esrc[i + g];
            uint4 va = *(const uint4*)(fb + (unsigned)ea * 256u + qoff);
            a0 += bflo(va.x); a1 += bfhi(va.x); a2 += bflo(va.y); a3 += bfhi(va.y);
            a4 += bflo(va.z); a5 += bfhi(va.z); a6 += bflo(va.w); a7 += bfhi(va.w);
        }
    }
    // reduce across 8 edge slots (xor lane bits 3,4,5)
    a0 += __shfl_xor(a0, 8);  a1 += __shfl_xor(a1, 8);
    a2 += __shfl_xor(a2, 8);  a3 += __shfl_xor(a3, 8);
    a4 += __shfl_xor(a4, 8);  a5 += __shfl_xor(a5, 8);
    a6 += __shfl_xor(a6, 8);  a7 += __shfl_xor(a7, 8);
    a0 += __shfl_xor(a0, 16); a1 += __shfl_xor(a1, 16);
    a2 += __shfl_xor(a2, 16); a3 += __shfl_xor(a3, 16);
    a4 += __shfl_xor(a4, 16); a5 += __shfl_xor(a5, 16);
    a6 += __shfl_xor(a6, 16); a7 += __shfl_xor(a7, 16);
    a0 += __shfl_xor(a0, 32); a1 += __shfl_xor(a1, 32);
    a2 += __shfl_xor(a2, 32); a3 += __shfl_xor(a3, 32);
    a4 += __shfl_xor(a4, 32); a5 += __shfl_xor(a5, 32);
    a6 += __shfl_xor(a6, 32); a7 += __shfl_xor(a7, 32);

    const float sc = invdeg[wid];
    a0 *= sc; a1 *= sc; a2 *= sc; a3 *= sc;
    a4 *= sc; a5 *= sc; a6 *= sc; a7 *= sc;
    unsigned p0, p1, p2, p3;
    asm("v_cvt_pk_bf16_f32 %0, %1, %2" : "=v"(p0) : "v"(a0), "v"(a1));
    asm("v_cvt_pk_bf16_f32 %0, %1, %2" : "=v"(p1) : "v"(a2), "v"(a3));
    asm("v_cvt_pk_bf16_f32 %0, %1, %2" : "=v"(p2) : "v"(a4), "v"(a5));
    asm("v_cvt_pk_bf16_f32 %0, %1, %2" : "=v"(p3) : "v"(a6), "v"(a7));
    if (g == 0) {
        uint4 o; o.x = p0; o.y = p1; o.z = p2; o.w = p3;
        *(uint4*)((char*)neigh + (size_t)wid * 256 + qoff) = o;
    }
}

// fallback fp32-source aggregate (only used if ws too small for xb)
__global__ __launch_bounds__(256) void k_agg_f32(const float* __restrict__ feat,
                                                 const int* __restrict__ esrc,
                                                 const int* __restrict__ offsets,
                                                 const float* __restrict__ invdeg,
                                                 unsigned short* __restrict__ neigh, int n) {
    int wid0 = (int)(((long long)blockIdx.x * blockDim.x + threadIdx.x) >> 6);
    const int wid = __builtin_amdgcn_readfirstlane(wid0);
    if (wid >= n) return;
    int lane = threadIdx.x & 63;
    int beg = offsets[wid], end = offsets[wid + 1];
    float a0 = 0.f, a1 = 0.f;
    for (int i = beg; i < end; ++i) {
        int s0 = esrc[i];
        float2 v0 = *(const float2*)(feat + (size_t)s0 * NF + lane * 2);
        a0 += v0.x; a1 += v0.y;
    }
    float sc = invdeg[wid];
    unsigned pk;
    float ca = a0 * sc, cb = a1 * sc;
    asm("v_cvt_pk_bf16_f32 %0, %1, %2" : "=v"(pk) : "v"(ca), "v"(cb));
    *(unsigned*)(neigh + (size_t)wid * NF + lane * 2) = pk;
}

// ================= MFMA GEMM: out = act(A1 @ W[0] + A2 @ W[1]) =================
// K=256 (k<128 from A1, k>=128 from A2=neigh). Bt[col][k] bf16.
// 256 threads = 4 waves; wave owns 32 rows x 128 cols (2 A-frags share each B-frag).
template <bool RELU, bool A1BF16, bool OUTBF16>
__global__ __launch_bounds__(256) void k_gemm_mfma(const void* __restrict__ A1v,
                                                   const unsigned short* __restrict__ A2,
                                                   const unsigned short* __restrict__ Bt,
                                                   void* __restrict__ outv, int nrows) {
    const int tid = threadIdx.x;
    const int wave = tid >> 6;
    const int lane = tid & 63;
    const int l15 = lane & 15;
    const int lk = lane >> 4;  // k-group 0..3
    const int rbase = blockIdx.x * 128 + wave * 32;

    f32x4 acc0[8], acc1[8];
#pragma unroll
    for (int t = 0; t < 8; ++t) { acc0[t] = (f32x4)0.0f; acc1[t] = (f32x4)0.0f; }

    const int ar0 = rbase + l15;
    const int ar1 = rbase + 16 + l15;
    const bool ok0 = ar0 < nrows;
    const bool ok1 = ar1 < nrows;

    for (int kc = 0; kc < 8; ++kc) {
        bf16x8 a0 = (bf16x8)(short)0, a1 = (bf16x8)(short)0;
        if (kc < 4) {
            if (A1BF16) {
                const unsigned short* A1 = (const unsigned short*)A1v;
                if (ok0) a0 = *(const bf16x8*)(A1 + (size_t)ar0 * NF + kc * 32 + lk * 8);
                if (ok1) a1 = *(const bf16x8*)(A1 + (size_t)ar1 * NF + kc * 32 + lk * 8);
            } else {
                const float* A1 = (const float*)A1v;
                if (ok0) {
                    const float* p = A1 + (size_t)ar0 * NF + kc * 32 + lk * 8;
                    float4 u = *(const float4*)p;
                    float4 v = *(const float4*)(p + 4);
                    a0[0] = (short)f2bf(u.x); a0[1] = (short)f2bf(u.y);
                    a0[2] = (short)f2bf(u.z); a0[3] = (short)f2bf(u.w);
                    a0[4] = (short)f2bf(v.x); a0[5] = (short)f2bf(v.y);
                    a0[6] = (short)f2bf(v.z); a0[7] = (short)f2bf(v.w);
                }
                if (ok1) {
                    const float* p = A1 + (size_t)ar1 * NF + kc * 32 + lk * 8;
                    float4 u = *(const float4*)p;
                    float4 v = *(const float4*)(p + 4);
                    a1[0] = (short)f2bf(u.x); a1[1] = (short)f2bf(u.y);
                    a1[2] = (short)f2bf(u.z); a1[3] = (short)f2bf(u.w);
                    a1[4] = (short)f2bf(v.x); a1[5] = (short)f2bf(v.y);
                    a1[6] = (short)f2bf(v.z); a1[7] = (short)f2bf(v.w);
                }
            }
        } else {
            if (ok0) a0 = *(const bf16x8*)(A2 + (size_t)ar0 * NF + (kc - 4) * 32 + lk * 8);
            if (ok1) a1 = *(const bf16x8*)(A2 + (size_t)ar1 * NF + (kc - 4) * 32 + lk * 8);
        }
#pragma unroll
        for (int t = 0; t < 8; ++t) {
            bf16x8 b = *(const bf16x8*)(Bt + (size_t)(t * 16 + l15) * 256 + kc * 32 + lk * 8);
            acc0[t] = __builtin_amdgcn_mfma_f32_16x16x32_bf16(a0, b, acc0[t], 0, 0, 0);
            acc1[t] = __builtin_amdgcn_mfma_f32_16x16x32_bf16(a1, b, acc1[t], 0, 0, 0);
        }
    }

#pragma unroll
    for (int f = 0; f < 2; ++f) {
        const int orow0 = rbase + f * 16 + lk * 4;
#pragma unroll
        for (int r = 0; r < 4; ++r) {
            int orow = orow0 + r;
            if (orow >= nrows) continue;
#pragma unroll
            for (int t = 0; t < 8; ++t) {
                float v = f ? acc1[t][r] : acc0[t][r];
                if (RELU) v = fmaxf(v, 0.f);
                if (OUTBF16)
                    ((unsigned short*)outv)[(size_t)orow * NF + t * 16 + l15] = f2bf(v);
                else
                    ((float*)outv)[(size_t)orow * NF + t * 16 + l15] = v;
            }
        }
    }
}

extern "C" void kernel_launch(void* const* d_in, const int* in_sizes, int n_in,
                              void* d_out, int out_size, void* d_ws, size_t ws_size,
                              hipStream_t stream) {
    const float* x = (const float*)d_in[0];
    const float* W_in = (const float*)d_in[1];
    const float* W_out = (const float*)d_in[2];
    const int* src = (const int*)d_in[3];
    const int* dst = (const int*)d_in[4];

    const int n = in_sizes[0] / NF;  // 100000  (must stay < 2^24 for packed CSR)
    const int E = in_sizes[3];       // 1600000
    float* outp = (float*)d_out;

    const int NB = (n + 255) >> NBSHIFT;
    const int nchunks = (E + CHUNK - 1) / CHUNK;

    // workspace carve
    char* ws = (char*)d_ws;
    size_t off = 0;
    auto take = [&](size_t bytes) {
        void* p = ws + off;
        off = (off + bytes + 511) & ~(size_t)511;
        return p;
    };
    int* gbhist = (int*)take((size_t)NB * 4);
    int* bbase = (int*)take((size_t)(NB + 1) * 4);
    int* gcursor = (int*)take((size_t)NB * 4);
    int* offsets = (int*)take((size_t)(n + 1) * 4);
    float* invdeg = (float*)take((size_t)n * 4);
    unsigned short* BtIn = (unsigned short*)take(128 * 256 * 2);
    unsigned short* BtOut = (unsigned short*)take(128 * 256 * 2);
    unsigned* gpairs = (unsigned*)take((size_t)E * 4);
    int* esrc = (int*)take((size_t)E * 4);
    unsigned short* hb = (unsigned short*)take((size_t)n * NF * 2);
    unsigned short* neigh = (unsigned short*)take((size_t)n * NF * 2);
    bool use_xb = (ws_size >= off + (size_t)n * NF * 2);
    unsigned short* xb = use_xb ? (unsigned short*)take((size_t)n * NF * 2) : nullptr;

    // ---- fused prep (bhist | buildBt | x->bf16) + CSR build ----
    hipMemsetAsync(gbhist, 0, (size_t)NB * 4, stream);
    const int cvtBlocks = use_xb ? (int)(((long long)n * NF / 8 + 255) / 256) : 0;
    k_prep<<<BH + BT + cvtBlocks, 256, 0, stream>>>(dst, E, NB, gbhist, x, xb,
                                                    W_in, W_out, BtIn, BtOut);
    k_bscan<<<1, 256, 0, stream>>>(gbhist, bbase, gcursor, NB, E, offsets, n);
    k_bucket<<<nchunks, 256, 0, stream>>>(src, dst, gcursor, gpairs, E);
    k_bsort<<<NB, 256, 0, stream>>>(gpairs, bbase, offsets, invdeg, esrc, n);

    const int aggBlocks = (n + 3) / 4;
    const int gemmBlocks = (n + 127) / 128;

    // ---- layer 0 ----
    if (use_xb) {
        k_agg_half<<<aggBlocks, 256, 0, stream>>>(xb, esrc, offsets, invdeg, neigh, n, 0);
        k_agg_half<<<aggBlocks, 256, 0, stream>>>(xb, esrc, offsets, invdeg, neigh, n, 1);
        k_gemm_mfma<true, true, true>
            <<<gemmBlocks, 256, 0, stream>>>(xb, neigh, BtIn, hb, n);
    } else {
        k_agg_f32<<<aggBlocks, 256, 0, stream>>>(x, esrc, offsets, invdeg, neigh, n);
        k_gemm_mfma<true, false, true>
            <<<gemmBlocks, 256, 0, stream>>>(x, neigh, BtIn, hb, n);
    }

    // ---- layer 1 ----
    k_agg_half<<<aggBlocks, 256, 0, stream>>>(hb, esrc, offsets, invdeg, neigh, n, 0);
    k_agg_half<<<aggBlocks, 256, 0, stream>>>(hb, esrc, offsets, invdeg, neigh, n, 1);
    k_gemm_mfma<false, true, false>
        <<<gemmBlocks, 256, 0, stream>>>(hb, neigh, BtOut, outp, n);
}

// Round 8
// 265.669 us; speedup vs baseline: 1.1633x; 1.1633x over previous
//
#include <hip/hip_runtime.h>

#define NF 128
#define NBSHIFT 8        // 256 nodes per bucket
#define NBMAX 512        // padded bucket count for scans
#define CHUNK 4096       // edges per multisplit chunk

typedef __attribute__((ext_vector_type(8))) short bf16x8;
typedef __attribute__((ext_vector_type(4))) float f32x4;

__device__ __forceinline__ unsigned short f2bf(float f) {
    unsigned int u = __builtin_bit_cast(unsigned int, f);
    u = (u + 0x7fffu + ((u >> 16) & 1u)) >> 16;
    return (unsigned short)u;
}
__device__ __forceinline__ float bflo(unsigned int u) {
    return __builtin_bit_cast(float, u << 16);
}
__device__ __forceinline__ float bfhi(unsigned int u) {
    return __builtin_bit_cast(float, u & 0xffff0000u);
}

// ================= fused prep: bhist | buildBt | cvt =================
#define BH 256
#define BT 256
__global__ __launch_bounds__(256) void k_prep(const int* __restrict__ dst, int E, int NB,
                                              int* __restrict__ gbhist,
                                              const float* __restrict__ x,
                                              unsigned short* __restrict__ xb,
                                              const float* __restrict__ Win,
                                              const float* __restrict__ Wout,
                                              unsigned short* __restrict__ BtIn,
                                              unsigned short* __restrict__ BtOut) {
    __shared__ int lh[NBMAX];
    const int bb = blockIdx.x;
    const int t = threadIdx.x;
    if (bb < BH) {
        for (int k = t; k < NBMAX; k += 256) lh[k] = 0;
        __syncthreads();
        for (int i = bb * 256 + t; i < E; i += BH * 256)
            atomicAdd(&lh[((unsigned)dst[i]) >> NBSHIFT], 1);
        __syncthreads();
        for (int k = t; k < NB; k += 256)
            if (lh[k]) atomicAdd(&gbhist[k], lh[k]);
    } else if (bb < BH + BT) {
        int b2 = bb - BH;
        const float* W = (b2 < 128) ? Win : Wout;
        unsigned short* Bt = (b2 < 128) ? BtIn : BtOut;
        int idx = (b2 & 127) * 256 + t;
        int c = idx >> 8;
        int k = idx & 255;
        int p = k >> 7, kk = k & 127;
        Bt[idx] = f2bf(W[((size_t)p * NF + kk) * NF + c]);
    } else {
        long long i = (long long)(bb - BH - BT) * 256 + t;
        const float4 a = *reinterpret_cast<const float4*>(x + i * 8);
        const float4 b = *reinterpret_cast<const float4*>(x + i * 8 + 4);
        union { unsigned short s[8]; uint4 u; } o;
        o.s[0] = f2bf(a.x); o.s[1] = f2bf(a.y); o.s[2] = f2bf(a.z); o.s[3] = f2bf(a.w);
        o.s[4] = f2bf(b.x); o.s[5] = f2bf(b.y); o.s[6] = f2bf(b.z); o.s[7] = f2bf(b.w);
        *reinterpret_cast<uint4*>(xb + i * 8) = o.u;
    }
}

// ================= CSR build =================

__global__ __launch_bounds__(256) void k_bscan(const int* __restrict__ gbhist,
                                               int* __restrict__ bbase, int* __restrict__ gcursor,
                                               int NB, int E, int* __restrict__ offsets, int n) {
    __shared__ int sA[NBMAX], sB[NBMAX];
    int t = threadIdx.x;
    for (int k = t; k < NBMAX; k += 256) sA[k] = (k < NB) ? gbhist[k] : 0;
    __syncthreads();
    int* pin = sA;
    int* pout = sB;
    for (int off = 1; off < NBMAX; off <<= 1) {
        for (int k = t; k < NBMAX; k += 256) pout[k] = pin[k] + (k >= off ? pin[k - off] : 0);
        __syncthreads();
        int* tmp = pin; pin = pout; pout = tmp;
    }
    for (int k = t; k < NB; k += 256) {
        int excl = pin[k] - gbhist[k];
        bbase[k] = excl;
        gcursor[k] = excl;
    }
    if (t == 0) {
        bbase[NB] = E;
        offsets[n] = E;
    }
}

// chunked multisplit; edge packed 32-bit: (dst&255)<<24 | src  (needs n < 2^24)
__global__ __launch_bounds__(256) void k_bucket(const int* __restrict__ src,
                                                const int* __restrict__ dst,
                                                int* __restrict__ gcursor,
                                                unsigned* __restrict__ gpairs, int E) {
    __shared__ int lhist[NBMAX], lbase[NBMAX], lcur[NBMAX], gb[NBMAX];
    __shared__ int sA[NBMAX], sB[NBMAX];
    __shared__ unsigned stage[CHUNK];
    __shared__ unsigned short stage_b[CHUNK];
    const int t = threadIdx.x;
    const int c0 = blockIdx.x * CHUNK;
    const int cc = min(CHUNK, E - c0);

    for (int k = t; k < NBMAX; k += 256) lhist[k] = 0;
    __syncthreads();

    int ls[16], ld[16];
#pragma unroll
    for (int j = 0; j < 16; ++j) {
        int i = t + j * 256;
        ls[j] = 0; ld[j] = 0;
        if (i < cc) {
            ls[j] = src[c0 + i];
            ld[j] = dst[c0 + i];
            atomicAdd(&lhist[((unsigned)ld[j]) >> NBSHIFT], 1);
        }
    }
    __syncthreads();
    for (int k = t; k < NBMAX; k += 256) sA[k] = lhist[k];
    __syncthreads();
    int* pin = sA;
    int* pout = sB;
    for (int off = 1; off < NBMAX; off <<= 1) {
        for (int k = t; k < NBMAX; k += 256) pout[k] = pin[k] + (k >= off ? pin[k - off] : 0);
        __syncthreads();
        int* tmp = pin; pin = pout; pout = tmp;
    }
    for (int k = t; k < NBMAX; k += 256) {
        int excl = pin[k] - lhist[k];
        lbase[k] = excl;
        lcur[k] = excl;
        int cnt = lhist[k];
        if (cnt > 0) gb[k] = atomicAdd(&gcursor[k], cnt);
    }
    __syncthreads();
#pragma unroll
    for (int j = 0; j < 16; ++j) {
        int i = t + j * 256;
        if (i < cc) {
            int b = ((unsigned)ld[j]) >> NBSHIFT;
            int pos = atomicAdd(&lcur[b], 1);
            stage[pos] = (((unsigned)ld[j] & 255u) << 24) | (unsigned)ls[j];
            stage_b[pos] = (unsigned short)b;
        }
    }
    __syncthreads();
    for (int idx = t; idx < cc; idx += 256) {
        unsigned p = stage[idx];
        int b = stage_b[idx];
        gpairs[gb[b] + (idx - lbase[b])] = p;
    }
}

// per-bucket: per-node hist + scan -> offsets/invdeg, scatter esrc within bucket region
__global__ __launch_bounds__(256) void k_bsort(const unsigned* __restrict__ gpairs,
                                               const int* __restrict__ bbase,
                                               int* __restrict__ offsets,
                                               float* __restrict__ invdeg,
                                               int* __restrict__ esrc, int n) {
    __shared__ int lcnt[256], lcur[256], sA[256], sB[256];
    const int b = blockIdx.x;
    const int t = threadIdx.x;
    const int base = bbase[b];
    const int c = bbase[b + 1] - base;
    const int n0 = b << NBSHIFT;

    lcnt[t] = 0;
    __syncthreads();
    for (int i = t; i < c; i += 256) {
        int node = (int)(gpairs[base + i] >> 24);
        atomicAdd(&lcnt[node], 1);
    }
    __syncthreads();
    sA[t] = lcnt[t];
    __syncthreads();
    int* pin = sA;
    int* pout = sB;
    for (int off = 1; off < 256; off <<= 1) {
        pout[t] = pin[t] + (t >= off ? pin[t - off] : 0);
        __syncthreads();
        int* tmp = pin; pin = pout; pout = tmp;
    }
    int excl = pin[t] - lcnt[t];
    lcur[t] = excl;
    int node_g = n0 + t;
    if (node_g < n) {
        offsets[node_g] = base + excl;
        invdeg[node_g] = 1.0f / (float)max(lcnt[t], 1);
    }
    __syncthreads();
    for (int i = t; i < c; i += 256) {
        unsigned p = gpairs[base + i];
        int node = (int)(p >> 24);
        int pos = atomicAdd(&lcur[node], 1);
        esrc[base + pos] = (int)(p & 0x00ffffffu);
    }
}

// ================= gather aggregation (bf16, 4 edges/load, full row) =================
// one wave per dst node; lane = (g = lane>>4: edge slot, q = lane&15: 16B col group).
__global__ __launch_bounds__(256) void k_agg_bf16(const unsigned short* __restrict__ feat,
                                                  const int* __restrict__ esrc,
                                                  const int* __restrict__ offsets,
                                                  const float* __restrict__ invdeg,
                                                  unsigned short* __restrict__ neigh, int n) {
    int wid0 = (int)(((long long)blockIdx.x * blockDim.x + threadIdx.x) >> 6);
    const int wid = __builtin_amdgcn_readfirstlane(wid0);
    if (wid >= n) return;
    const int lane = threadIdx.x & 63;
    const int g = lane >> 4;        // edge slot within quad
    const int q = lane & 15;        // column group: bytes [q*16, q*16+16)
    const unsigned qoff = (unsigned)q * 16u;
    const char* fb = (const char*)feat;

    const int beg = offsets[wid];
    const int end = offsets[wid + 1];
    float a0 = 0.f, a1 = 0.f, a2 = 0.f, a3 = 0.f, a4 = 0.f, a5 = 0.f, a6 = 0.f, a7 = 0.f;

    int i = beg;
    for (; i + 16 <= end; i += 16) {
        int e[16];
#pragma unroll
        for (int j = 0; j < 16; ++j) e[j] = esrc[i + j];
#pragma unroll
        for (int u = 0; u < 4; ++u) {
            int es = (g & 2) ? ((g & 1) ? e[u * 4 + 3] : e[u * 4 + 2])
                             : ((g & 1) ? e[u * 4 + 1] : e[u * 4 + 0]);
            uint4 v = *(const uint4*)(fb + (unsigned)es * 256u + qoff);
            a0 += bflo(v.x); a1 += bfhi(v.x);
            a2 += bflo(v.y); a3 += bfhi(v.y);
            a4 += bflo(v.z); a5 += bfhi(v.z);
            a6 += bflo(v.w); a7 += bfhi(v.w);
        }
    }
    for (; i + 4 <= end; i += 4) {
        int e0 = esrc[i + 0], e1 = esrc[i + 1], e2 = esrc[i + 2], e3 = esrc[i + 3];
        int es = (g & 2) ? ((g & 1) ? e3 : e2) : ((g & 1) ? e1 : e0);
        uint4 v = *(const uint4*)(fb + (unsigned)es * 256u + qoff);
        a0 += bflo(v.x); a1 += bfhi(v.x);
        a2 += bflo(v.y); a3 += bfhi(v.y);
        a4 += bflo(v.z); a5 += bfhi(v.z);
        a6 += bflo(v.w); a7 += bfhi(v.w);
    }
    if (i < end) {
        int r = end - i;  // 1..3
        if (g < r) {
            int es = esrc[i + g];
            uint4 v = *(const uint4*)(fb + (unsigned)es * 256u + qoff);
            a0 += bflo(v.x); a1 += bfhi(v.x);
            a2 += bflo(v.y); a3 += bfhi(v.y);
            a4 += bflo(v.z); a5 += bfhi(v.z);
            a6 += bflo(v.w); a7 += bfhi(v.w);
        }
    }
    // reduce across the 4 edge slots (lanes q, 16+q, 32+q, 48+q)
    a0 += __shfl_xor(a0, 16); a1 += __shfl_xor(a1, 16);
    a2 += __shfl_xor(a2, 16); a3 += __shfl_xor(a3, 16);
    a4 += __shfl_xor(a4, 16); a5 += __shfl_xor(a5, 16);
    a6 += __shfl_xor(a6, 16); a7 += __shfl_xor(a7, 16);
    a0 += __shfl_xor(a0, 32); a1 += __shfl_xor(a1, 32);
    a2 += __shfl_xor(a2, 32); a3 += __shfl_xor(a3, 32);
    a4 += __shfl_xor(a4, 32); a5 += __shfl_xor(a5, 32);
    a6 += __shfl_xor(a6, 32); a7 += __shfl_xor(a7, 32);

    const float sc = invdeg[wid];
    a0 *= sc; a1 *= sc; a2 *= sc; a3 *= sc;
    a4 *= sc; a5 *= sc; a6 *= sc; a7 *= sc;
    unsigned p0, p1, p2, p3;
    asm("v_cvt_pk_bf16_f32 %0, %1, %2" : "=v"(p0) : "v"(a0), "v"(a1));
    asm("v_cvt_pk_bf16_f32 %0, %1, %2" : "=v"(p1) : "v"(a2), "v"(a3));
    asm("v_cvt_pk_bf16_f32 %0, %1, %2" : "=v"(p2) : "v"(a4), "v"(a5));
    asm("v_cvt_pk_bf16_f32 %0, %1, %2" : "=v"(p3) : "v"(a6), "v"(a7));
    if (g == 0) {
        uint4 o; o.x = p0; o.y = p1; o.z = p2; o.w = p3;
        *(uint4*)((char*)neigh + (size_t)wid * 256 + qoff) = o;
    }
}

// fallback fp32-source aggregate (only used if ws too small for xb)
__global__ __launch_bounds__(256) void k_agg_f32(const float* __restrict__ feat,
                                                 const int* __restrict__ esrc,
                                                 const int* __restrict__ offsets,
                                                 const float* __restrict__ invdeg,
                                                 unsigned short* __restrict__ neigh, int n) {
    int wid0 = (int)(((long long)blockIdx.x * blockDim.x + threadIdx.x) >> 6);
    const int wid = __builtin_amdgcn_readfirstlane(wid0);
    if (wid >= n) return;
    int lane = threadIdx.x & 63;
    int beg = offsets[wid], end = offsets[wid + 1];
    float a0 = 0.f, a1 = 0.f;
    for (int i = beg; i < end; ++i) {
        int s0 = esrc[i];
        float2 v0 = *(const float2*)(feat + (size_t)s0 * NF + lane * 2);
        a0 += v0.x; a1 += v0.y;
    }
    float sc = invdeg[wid];
    unsigned pk;
    float ca = a0 * sc, cb = a1 * sc;
    asm("v_cvt_pk_bf16_f32 %0, %1, %2" : "=v"(pk) : "v"(ca), "v"(cb));
    *(unsigned*)(neigh + (size_t)wid * NF + lane * 2) = pk;
}

// ================= MFMA GEMM, B-stationary: out = act(A1 @ W[0] + A2 @ W[1]) ========
// K=256 (k<128 from A1, k>=128 from A2=neigh). Bt[col][k] bf16.
// Block = 256 thr = 4 waves; wave owns cols [wave*32, wave*32+32) x rows [rbase, rbase+64).
// Wave preloads its whole B panel (32 cols x 256 k = 16 frags = 64 VGPR) ONCE;
// inner loop = 4 row-chunks of {8 independent A-loads -> 16 MFMAs}.
template <bool RELU, bool A1BF16, bool OUTBF16>
__global__ __launch_bounds__(256) void k_gemm_mfma(const void* __restrict__ A1v,
                                                   const unsigned short* __restrict__ A2,
                                                   const unsigned short* __restrict__ Bt,
                                                   void* __restrict__ outv, int nrows) {
    const int tid = threadIdx.x;
    const int wave = tid >> 6;
    const int lane = tid & 63;
    const int l15 = lane & 15;
    const int lk = lane >> 4;  // k-group 0..3
    const int col0 = wave * 32;
    const int rbase = blockIdx.x * 64;

    bf16x8 breg[2][8];
#pragma unroll
    for (int c = 0; c < 2; ++c)
#pragma unroll
        for (int kc = 0; kc < 8; ++kc)
            breg[c][kc] = *(const bf16x8*)(Bt + (size_t)(col0 + c * 16 + l15) * 256 +
                                           kc * 32 + lk * 8);

    f32x4 acc[4][2];
#pragma unroll
    for (int rc = 0; rc < 4; ++rc) {
        acc[rc][0] = (f32x4)0.0f;
        acc[rc][1] = (f32x4)0.0f;
    }

#pragma unroll
    for (int rc = 0; rc < 4; ++rc) {
        const int arow = rbase + rc * 16 + l15;
        const bool ok = arow < nrows;
        bf16x8 a[8];
        if (ok) {
            if (A1BF16) {
                const unsigned short* A1 = (const unsigned short*)A1v;
#pragma unroll
                for (int kc = 0; kc < 4; ++kc) {
                    a[kc] = *(const bf16x8*)(A1 + (size_t)arow * NF + kc * 32 + lk * 8);
                    a[kc + 4] = *(const bf16x8*)(A2 + (size_t)arow * NF + kc * 32 + lk * 8);
                }
            } else {
                const float* A1 = (const float*)A1v;
#pragma unroll
                for (int kc = 0; kc < 4; ++kc) {
                    const float* p = A1 + (size_t)arow * NF + kc * 32 + lk * 8;
                    float4 u = *(const float4*)p;
                    float4 v = *(const float4*)(p + 4);
                    a[kc][0] = (short)f2bf(u.x); a[kc][1] = (short)f2bf(u.y);
                    a[kc][2] = (short)f2bf(u.z); a[kc][3] = (short)f2bf(u.w);
                    a[kc][4] = (short)f2bf(v.x); a[kc][5] = (short)f2bf(v.y);
                    a[kc][6] = (short)f2bf(v.z); a[kc][7] = (short)f2bf(v.w);
                    a[kc + 4] = *(const bf16x8*)(A2 + (size_t)arow * NF + kc * 32 + lk * 8);
                }
            }
        } else {
#pragma unroll
            for (int kc = 0; kc < 8; ++kc) a[kc] = (bf16x8)(short)0;
        }
#pragma unroll
        for (int kc = 0; kc < 8; ++kc) {
            acc[rc][0] = __builtin_amdgcn_mfma_f32_16x16x32_bf16(a[kc], breg[0][kc],
                                                                 acc[rc][0], 0, 0, 0);
            acc[rc][1] = __builtin_amdgcn_mfma_f32_16x16x32_bf16(a[kc], breg[1][kc],
                                                                 acc[rc][1], 0, 0, 0);
        }
    }

#pragma unroll
    for (int rc = 0; rc < 4; ++rc) {
#pragma unroll
        for (int r = 0; r < 4; ++r) {
            const int orow = rbase + rc * 16 + lk * 4 + r;
            if (orow >= nrows) continue;
#pragma unroll
            for (int c = 0; c < 2; ++c) {
                float v = acc[rc][c][r];
                if (RELU) v = fmaxf(v, 0.f);
                const int col = col0 + c * 16 + l15;
                if (OUTBF16)
                    ((unsigned short*)outv)[(size_t)orow * NF + col] = f2bf(v);
                else
                    ((float*)outv)[(size_t)orow * NF + col] = v;
            }
        }
    }
}

extern "C" void kernel_launch(void* const* d_in, const int* in_sizes, int n_in,
                              void* d_out, int out_size, void* d_ws, size_t ws_size,
                              hipStream_t stream) {
    const float* x = (const float*)d_in[0];
    const float* W_in = (const float*)d_in[1];
    const float* W_out = (const float*)d_in[2];
    const int* src = (const int*)d_in[3];
    const int* dst = (const int*)d_in[4];

    const int n = in_sizes[0] / NF;  // 100000  (must stay < 2^24 for packed CSR)
    const int E = in_sizes[3];       // 1600000
    float* outp = (float*)d_out;

    const int NB = (n + 255) >> NBSHIFT;
    const int nchunks = (E + CHUNK - 1) / CHUNK;

    // workspace carve
    char* ws = (char*)d_ws;
    size_t off = 0;
    auto take = [&](size_t bytes) {
        void* p = ws + off;
        off = (off + bytes + 511) & ~(size_t)511;
        return p;
    };
    int* gbhist = (int*)take((size_t)NB * 4);
    int* bbase = (int*)take((size_t)(NB + 1) * 4);
    int* gcursor = (int*)take((size_t)NB * 4);
    int* offsets = (int*)take((size_t)(n + 1) * 4);
    float* invdeg = (float*)take((size_t)n * 4);
    unsigned short* BtIn = (unsigned short*)take(128 * 256 * 2);
    unsigned short* BtOut = (unsigned short*)take(128 * 256 * 2);
    unsigned* gpairs = (unsigned*)take((size_t)E * 4);
    int* esrc = (int*)take((size_t)E * 4);
    unsigned short* hb = (unsigned short*)take((size_t)n * NF * 2);
    unsigned short* neigh = (unsigned short*)take((size_t)n * NF * 2);
    bool use_xb = (ws_size >= off + (size_t)n * NF * 2);
    unsigned short* xb = use_xb ? (unsigned short*)take((size_t)n * NF * 2) : nullptr;

    // ---- fused prep (bhist | buildBt | x->bf16) + CSR build ----
    hipMemsetAsync(gbhist, 0, (size_t)NB * 4, stream);
    const int cvtBlocks = use_xb ? (int)(((long long)n * NF / 8 + 255) / 256) : 0;
    k_prep<<<BH + BT + cvtBlocks, 256, 0, stream>>>(dst, E, NB, gbhist, x, xb,
                                                    W_in, W_out, BtIn, BtOut);
    k_bscan<<<1, 256, 0, stream>>>(gbhist, bbase, gcursor, NB, E, offsets, n);
    k_bucket<<<nchunks, 256, 0, stream>>>(src, dst, gcursor, gpairs, E);
    k_bsort<<<NB, 256, 0, stream>>>(gpairs, bbase, offsets, invdeg, esrc, n);

    const int aggBlocks = (n + 3) / 4;
    const int gemmBlocks = (n + 63) / 64;

    // ---- layer 0 ----
    if (use_xb) {
        k_agg_bf16<<<aggBlocks, 256, 0, stream>>>(xb, esrc, offsets, invdeg, neigh, n);
        k_gemm_mfma<true, true, true>
            <<<gemmBlocks, 256, 0, stream>>>(xb, neigh, BtIn, hb, n);
    } else {
        k_agg_f32<<<aggBlocks, 256, 0, stream>>>(x, esrc, offsets, invdeg, neigh, n);
        k_gemm_mfma<true, false, true>
            <<<gemmBlocks, 256, 0, stream>>>(x, neigh, BtIn, hb, n);
    }

    // ---- layer 1 ----
    k_agg_bf16<<<aggBlocks, 256, 0, stream>>>(hb, esrc, offsets, invdeg, neigh, n);
    k_gemm_mfma<false, true, false>
        <<<gemmBlocks, 256, 0, stream>>>(hb, neigh, BtOut, outp, n);
}

// Round 9
// 240.023 us; speedup vs baseline: 1.2876x; 1.1068x over previous
//
#include <hip/hip_runtime.h>

#define NF 128
#define NBSHIFT 8        // 256 nodes per bucket
#define NBMAX 512        // padded bucket count for scans
#define CHUNK 4096       // edges per multisplit chunk

typedef __attribute__((ext_vector_type(8))) short bf16x8;
typedef __attribute__((ext_vector_type(4))) float f32x4;
typedef __attribute__((ext_vector_type(2))) float f32x2;

__device__ __forceinline__ unsigned short f2bf(float f) {
    unsigned int u = __builtin_bit_cast(unsigned int, f);
    u = (u + 0x7fffu + ((u >> 16) & 1u)) >> 16;
    return (unsigned short)u;
}
__device__ __forceinline__ float bflo(unsigned int u) {
    return __builtin_bit_cast(float, u << 16);
}
__device__ __forceinline__ float bfhi(unsigned int u) {
    return __builtin_bit_cast(float, u & 0xffff0000u);
}
__device__ __forceinline__ unsigned char f2fp8(float v) {
    return (unsigned char)(__builtin_amdgcn_cvt_pk_fp8_f32(v, v, 0, false) & 0xff);
}

// ================= fused prep: bhist | buildBt | cvt(x -> bf16 + fp8) =================
#define BH 256
#define BT 256
__global__ __launch_bounds__(256) void k_prep(const int* __restrict__ dst, int E, int NB,
                                              int* __restrict__ gbhist,
                                              const float* __restrict__ x,
                                              unsigned short* __restrict__ xb,
                                              unsigned char* __restrict__ xq,
                                              const float* __restrict__ Win,
                                              const float* __restrict__ Wout,
                                              unsigned short* __restrict__ BtIn,
                                              unsigned short* __restrict__ BtOut) {
    __shared__ int lh[NBMAX];
    const int bb = blockIdx.x;
    const int t = threadIdx.x;
    if (bb < BH) {
        for (int k = t; k < NBMAX; k += 256) lh[k] = 0;
        __syncthreads();
        for (int i = bb * 256 + t; i < E; i += BH * 256)
            atomicAdd(&lh[((unsigned)dst[i]) >> NBSHIFT], 1);
        __syncthreads();
        for (int k = t; k < NB; k += 256)
            if (lh[k]) atomicAdd(&gbhist[k], lh[k]);
    } else if (bb < BH + BT) {
        int b2 = bb - BH;
        const float* W = (b2 < 128) ? Win : Wout;
        unsigned short* Bt = (b2 < 128) ? BtIn : BtOut;
        int idx = (b2 & 127) * 256 + t;
        int c = idx >> 8;
        int k = idx & 255;
        int p = k >> 7, kk = k & 127;
        Bt[idx] = f2bf(W[((size_t)p * NF + kk) * NF + c]);
    } else {
        long long i = (long long)(bb - BH - BT) * 256 + t;
        const float4 a = *reinterpret_cast<const float4*>(x + i * 8);
        const float4 b = *reinterpret_cast<const float4*>(x + i * 8 + 4);
        union { unsigned short s[8]; uint4 u; } o;
        o.s[0] = f2bf(a.x); o.s[1] = f2bf(a.y); o.s[2] = f2bf(a.z); o.s[3] = f2bf(a.w);
        o.s[4] = f2bf(b.x); o.s[5] = f2bf(b.y); o.s[6] = f2bf(b.z); o.s[7] = f2bf(b.w);
        *reinterpret_cast<uint4*>(xb + i * 8) = o.u;
        int lo = __builtin_amdgcn_cvt_pk_fp8_f32(a.x, a.y, 0, false);
        lo = __builtin_amdgcn_cvt_pk_fp8_f32(a.z, a.w, lo, true);
        int hi = __builtin_amdgcn_cvt_pk_fp8_f32(b.x, b.y, 0, false);
        hi = __builtin_amdgcn_cvt_pk_fp8_f32(b.z, b.w, hi, true);
        uint2 oq; oq.x = (unsigned)lo; oq.y = (unsigned)hi;
        *reinterpret_cast<uint2*>(xq + i * 8) = oq;
    }
}

// ================= CSR build =================

__global__ __launch_bounds__(256) void k_bscan(const int* __restrict__ gbhist,
                                               int* __restrict__ bbase, int* __restrict__ gcursor,
                                               int NB, int E, int* __restrict__ offsets, int n) {
    __shared__ int sA[NBMAX], sB[NBMAX];
    int t = threadIdx.x;
    for (int k = t; k < NBMAX; k += 256) sA[k] = (k < NB) ? gbhist[k] : 0;
    __syncthreads();
    int* pin = sA;
    int* pout = sB;
    for (int off = 1; off < NBMAX; off <<= 1) {
        for (int k = t; k < NBMAX; k += 256) pout[k] = pin[k] + (k >= off ? pin[k - off] : 0);
        __syncthreads();
        int* tmp = pin; pin = pout; pout = tmp;
    }
    for (int k = t; k < NB; k += 256) {
        int excl = pin[k] - gbhist[k];
        bbase[k] = excl;
        gcursor[k] = excl;
    }
    if (t == 0) {
        bbase[NB] = E;
        offsets[n] = E;
    }
}

// chunked multisplit; edge packed 32-bit: (dst&255)<<24 | src  (needs n < 2^24)
__global__ __launch_bounds__(256) void k_bucket(const int* __restrict__ src,
                                                const int* __restrict__ dst,
                                                int* __restrict__ gcursor,
                                                unsigned* __restrict__ gpairs, int E) {
    __shared__ int lhist[NBMAX], lbase[NBMAX], lcur[NBMAX], gb[NBMAX];
    __shared__ int sA[NBMAX], sB[NBMAX];
    __shared__ unsigned stage[CHUNK];
    __shared__ unsigned short stage_b[CHUNK];
    const int t = threadIdx.x;
    const int c0 = blockIdx.x * CHUNK;
    const int cc = min(CHUNK, E - c0);

    for (int k = t; k < NBMAX; k += 256) lhist[k] = 0;
    __syncthreads();

    int ls[16], ld[16];
#pragma unroll
    for (int j = 0; j < 16; ++j) {
        int i = t + j * 256;
        ls[j] = 0; ld[j] = 0;
        if (i < cc) {
            ls[j] = src[c0 + i];
            ld[j] = dst[c0 + i];
            atomicAdd(&lhist[((unsigned)ld[j]) >> NBSHIFT], 1);
        }
    }
    __syncthreads();
    for (int k = t; k < NBMAX; k += 256) sA[k] = lhist[k];
    __syncthreads();
    int* pin = sA;
    int* pout = sB;
    for (int off = 1; off < NBMAX; off <<= 1) {
        for (int k = t; k < NBMAX; k += 256) pout[k] = pin[k] + (k >= off ? pin[k - off] : 0);
        __syncthreads();
        int* tmp = pin; pin = pout; pout = tmp;
    }
    for (int k = t; k < NBMAX; k += 256) {
        int excl = pin[k] - lhist[k];
        lbase[k] = excl;
        lcur[k] = excl;
        int cnt = lhist[k];
        if (cnt > 0) gb[k] = atomicAdd(&gcursor[k], cnt);
    }
    __syncthreads();
#pragma unroll
    for (int j = 0; j < 16; ++j) {
        int i = t + j * 256;
        if (i < cc) {
            int b = ((unsigned)ld[j]) >> NBSHIFT;
            int pos = atomicAdd(&lcur[b], 1);
            stage[pos] = (((unsigned)ld[j] & 255u) << 24) | (unsigned)ls[j];
            stage_b[pos] = (unsigned short)b;
        }
    }
    __syncthreads();
    for (int idx = t; idx < cc; idx += 256) {
        unsigned p = stage[idx];
        int b = stage_b[idx];
        gpairs[gb[b] + (idx - lbase[b])] = p;
    }
}

// per-bucket: per-node hist + scan -> offsets/invdeg, scatter esrc within bucket region
__global__ __launch_bounds__(256) void k_bsort(const unsigned* __restrict__ gpairs,
                                               const int* __restrict__ bbase,
                                               int* __restrict__ offsets,
                                               float* __restrict__ invdeg,
                                               int* __restrict__ esrc, int n) {
    __shared__ int lcnt[256], lcur[256], sA[256], sB[256];
    const int b = blockIdx.x;
    const int t = threadIdx.x;
    const int base = bbase[b];
    const int c = bbase[b + 1] - base;
    const int n0 = b << NBSHIFT;

    lcnt[t] = 0;
    __syncthreads();
    for (int i = t; i < c; i += 256) {
        int node = (int)(gpairs[base + i] >> 24);
        atomicAdd(&lcnt[node], 1);
    }
    __syncthreads();
    sA[t] = lcnt[t];
    __syncthreads();
    int* pin = sA;
    int* pout = sB;
    for (int off = 1; off < 256; off <<= 1) {
        pout[t] = pin[t] + (t >= off ? pin[t - off] : 0);
        __syncthreads();
        int* tmp = pin; pin = pout; pout = tmp;
    }
    int excl = pin[t] - lcnt[t];
    lcur[t] = excl;
    int node_g = n0 + t;
    if (node_g < n) {
        offsets[node_g] = base + excl;
        invdeg[node_g] = 1.0f / (float)max(lcnt[t], 1);
    }
    __syncthreads();
    for (int i = t; i < c; i += 256) {
        unsigned p = gpairs[base + i];
        int node = (int)(p >> 24);
        int pos = atomicAdd(&lcur[node], 1);
        esrc[base + pos] = (int)(p & 0x00ffffffu);
    }
}

// ================= gather aggregation (fp8 source, 4 edges/load) =================
// one wave per dst node; lane = (g = lane>>4: edge slot, q = lane&15: 8B col group).
// fp8 row = 128B; one uint2 load/lane fetches 4 full rows per wave instruction.
__global__ __launch_bounds__(256) void k_agg_fp8(const unsigned char* __restrict__ feat,
                                                 const int* __restrict__ esrc,
                                                 const int* __restrict__ offsets,
                                                 const float* __restrict__ invdeg,
                                                 unsigned short* __restrict__ neigh, int n) {
    int wid0 = (int)(((long long)blockIdx.x * blockDim.x + threadIdx.x) >> 6);
    const int wid = __builtin_amdgcn_readfirstlane(wid0);
    if (wid >= n) return;
    const int lane = threadIdx.x & 63;
    const int g = lane >> 4;        // edge slot within quad
    const int q = lane & 15;        // column group: fp8 bytes [q*8, q*8+8) = cols 8q..8q+7
    const unsigned qoff = (unsigned)q * 8u;
    const unsigned char* fb = feat;

    const int beg = offsets[wid];
    const int end = offsets[wid + 1];
    f32x2 c01 = {0.f, 0.f}, c23 = {0.f, 0.f}, c45 = {0.f, 0.f}, c67 = {0.f, 0.f};

    int i = beg;
    for (; i + 16 <= end; i += 16) {
        int e[16];
#pragma unroll
        for (int j = 0; j < 16; ++j) e[j] = esrc[i + j];
#pragma unroll
        for (int u = 0; u < 4; ++u) {
            int es = (g & 2) ? ((g & 1) ? e[u * 4 + 3] : e[u * 4 + 2])
                             : ((g & 1) ? e[u * 4 + 1] : e[u * 4 + 0]);
            uint2 v = *(const uint2*)(fb + (unsigned)es * 128u + qoff);
            c01 += __builtin_amdgcn_cvt_pk_f32_fp8((int)v.x, false);
            c23 += __builtin_amdgcn_cvt_pk_f32_fp8((int)v.x, true);
            c45 += __builtin_amdgcn_cvt_pk_f32_fp8((int)v.y, false);
            c67 += __builtin_amdgcn_cvt_pk_f32_fp8((int)v.y, true);
        }
    }
    for (; i + 4 <= end; i += 4) {
        int e0 = esrc[i + 0], e1 = esrc[i + 1], e2 = esrc[i + 2], e3 = esrc[i + 3];
        int es = (g & 2) ? ((g & 1) ? e3 : e2) : ((g & 1) ? e1 : e0);
        uint2 v = *(const uint2*)(fb + (unsigned)es * 128u + qoff);
        c01 += __builtin_amdgcn_cvt_pk_f32_fp8((int)v.x, false);
        c23 += __builtin_amdgcn_cvt_pk_f32_fp8((int)v.x, true);
        c45 += __builtin_amdgcn_cvt_pk_f32_fp8((int)v.y, false);
        c67 += __builtin_amdgcn_cvt_pk_f32_fp8((int)v.y, true);
    }
    if (i < end) {
        int r = end - i;  // 1..3
        if (g < r) {
            int es = esrc[i + g];
            uint2 v = *(const uint2*)(fb + (unsigned)es * 128u + qoff);
            c01 += __builtin_amdgcn_cvt_pk_f32_fp8((int)v.x, false);
            c23 += __builtin_amdgcn_cvt_pk_f32_fp8((int)v.x, true);
            c45 += __builtin_amdgcn_cvt_pk_f32_fp8((int)v.y, false);
            c67 += __builtin_amdgcn_cvt_pk_f32_fp8((int)v.y, true);
        }
    }
    float a0 = c01.x, a1 = c01.y, a2 = c23.x, a3 = c23.y;
    float a4 = c45.x, a5 = c45.y, a6 = c67.x, a7 = c67.y;
    // reduce across the 4 edge slots (lanes q, 16+q, 32+q, 48+q)
    a0 += __shfl_xor(a0, 16); a1 += __shfl_xor(a1, 16);
    a2 += __shfl_xor(a2, 16); a3 += __shfl_xor(a3, 16);
    a4 += __shfl_xor(a4, 16); a5 += __shfl_xor(a5, 16);
    a6 += __shfl_xor(a6, 16); a7 += __shfl_xor(a7, 16);
    a0 += __shfl_xor(a0, 32); a1 += __shfl_xor(a1, 32);
    a2 += __shfl_xor(a2, 32); a3 += __shfl_xor(a3, 32);
    a4 += __shfl_xor(a4, 32); a5 += __shfl_xor(a5, 32);
    a6 += __shfl_xor(a6, 32); a7 += __shfl_xor(a7, 32);

    const float sc = invdeg[wid];
    a0 *= sc; a1 *= sc; a2 *= sc; a3 *= sc;
    a4 *= sc; a5 *= sc; a6 *= sc; a7 *= sc;
    unsigned p0, p1, p2, p3;
    asm("v_cvt_pk_bf16_f32 %0, %1, %2" : "=v"(p0) : "v"(a0), "v"(a1));
    asm("v_cvt_pk_bf16_f32 %0, %1, %2" : "=v"(p1) : "v"(a2), "v"(a3));
    asm("v_cvt_pk_bf16_f32 %0, %1, %2" : "=v"(p2) : "v"(a4), "v"(a5));
    asm("v_cvt_pk_bf16_f32 %0, %1, %2" : "=v"(p3) : "v"(a6), "v"(a7));
    if (g == 0) {
        uint4 o; o.x = p0; o.y = p1; o.z = p2; o.w = p3;
        *(uint4*)((char*)neigh + (size_t)wid * 256 + (unsigned)q * 16u) = o;
    }
}

// fallback bf16-source aggregate (used only if ws too small for the fp8 path)
__global__ __launch_bounds__(256) void k_agg_bf16(const unsigned short* __restrict__ feat,
                                                  const int* __restrict__ esrc,
                                                  const int* __restrict__ offsets,
                                                  const float* __restrict__ invdeg,
                                                  unsigned short* __restrict__ neigh, int n) {
    int wid0 = (int)(((long long)blockIdx.x * blockDim.x + threadIdx.x) >> 6);
    const int wid = __builtin_amdgcn_readfirstlane(wid0);
    if (wid >= n) return;
    const int lane = threadIdx.x & 63;
    const int g = lane >> 4;
    const int q = lane & 15;
    const unsigned qoff = (unsigned)q * 16u;
    const char* fb = (const char*)feat;
    const int beg = offsets[wid];
    const int end = offsets[wid + 1];
    float a0 = 0.f, a1 = 0.f, a2 = 0.f, a3 = 0.f, a4 = 0.f, a5 = 0.f, a6 = 0.f, a7 = 0.f;
    int i = beg;
    for (; i + 4 <= end; i += 4) {
        int e0 = esrc[i + 0], e1 = esrc[i + 1], e2 = esrc[i + 2], e3 = esrc[i + 3];
        int es = (g & 2) ? ((g & 1) ? e3 : e2) : ((g & 1) ? e1 : e0);
        uint4 v = *(const uint4*)(fb + (unsigned)es * 256u + qoff);
        a0 += bflo(v.x); a1 += bfhi(v.x);
        a2 += bflo(v.y); a3 += bfhi(v.y);
        a4 += bflo(v.z); a5 += bfhi(v.z);
        a6 += bflo(v.w); a7 += bfhi(v.w);
    }
    if (i < end) {
        int r = end - i;
        if (g < r) {
            int es = esrc[i + g];
            uint4 v = *(const uint4*)(fb + (unsigned)es * 256u + qoff);
            a0 += bflo(v.x); a1 += bfhi(v.x);
            a2 += bflo(v.y); a3 += bfhi(v.y);
            a4 += bflo(v.z); a5 += bfhi(v.z);
            a6 += bflo(v.w); a7 += bfhi(v.w);
        }
    }
    a0 += __shfl_xor(a0, 16); a1 += __shfl_xor(a1, 16);
    a2 += __shfl_xor(a2, 16); a3 += __shfl_xor(a3, 16);
    a4 += __shfl_xor(a4, 16); a5 += __shfl_xor(a5, 16);
    a6 += __shfl_xor(a6, 16); a7 += __shfl_xor(a7, 16);
    a0 += __shfl_xor(a0, 32); a1 += __shfl_xor(a1, 32);
    a2 += __shfl_xor(a2, 32); a3 += __shfl_xor(a3, 32);
    a4 += __shfl_xor(a4, 32); a5 += __shfl_xor(a5, 32);
    a6 += __shfl_xor(a6, 32); a7 += __shfl_xor(a7, 32);
    const float sc = invdeg[wid];
    a0 *= sc; a1 *= sc; a2 *= sc; a3 *= sc;
    a4 *= sc; a5 *= sc; a6 *= sc; a7 *= sc;
    unsigned p0, p1, p2, p3;
    asm("v_cvt_pk_bf16_f32 %0, %1, %2" : "=v"(p0) : "v"(a0), "v"(a1));
    asm("v_cvt_pk_bf16_f32 %0, %1, %2" : "=v"(p1) : "v"(a2), "v"(a3));
    asm("v_cvt_pk_bf16_f32 %0, %1, %2" : "=v"(p2) : "v"(a4), "v"(a5));
    asm("v_cvt_pk_bf16_f32 %0, %1, %2" : "=v"(p3) : "v"(a6), "v"(a7));
    if (g == 0) {
        uint4 o; o.x = p0; o.y = p1; o.z = p2; o.w = p3;
        *(uint4*)((char*)neigh + (size_t)wid * 256 + qoff) = o;
    }
}

// fallback fp32-source aggregate
__global__ __launch_bounds__(256) void k_agg_f32(const float* __restrict__ feat,
                                                 const int* __restrict__ esrc,
                                                 const int* __restrict__ offsets,
                                                 const float* __restrict__ invdeg,
                                                 unsigned short* __restrict__ neigh, int n) {
    int wid0 = (int)(((long long)blockIdx.x * blockDim.x + threadIdx.x) >> 6);
    const int wid = __builtin_amdgcn_readfirstlane(wid0);
    if (wid >= n) return;
    int lane = threadIdx.x & 63;
    int beg = offsets[wid], end = offsets[wid + 1];
    float a0 = 0.f, a1 = 0.f;
    for (int i = beg; i < end; ++i) {
        int s0 = esrc[i];
        float2 v0 = *(const float2*)(feat + (size_t)s0 * NF + lane * 2);
        a0 += v0.x; a1 += v0.y;
    }
    float sc = invdeg[wid];
    unsigned pk;
    float ca = a0 * sc, cb = a1 * sc;
    asm("v_cvt_pk_bf16_f32 %0, %1, %2" : "=v"(pk) : "v"(ca), "v"(cb));
    *(unsigned*)(neigh + (size_t)wid * NF + lane * 2) = pk;
}

// ================= MFMA GEMM, B-stationary: out = act(A1 @ W[0] + A2 @ W[1]) ========
// Optionally also writes the fp8 image of the output (for the next layer's gather).
template <bool RELU, bool A1BF16, bool OUTBF16, bool WRITEQ>
__global__ __launch_bounds__(256) void k_gemm_mfma(const void* __restrict__ A1v,
                                                   const unsigned short* __restrict__ A2,
                                                   const unsigned short* __restrict__ Bt,
                                                   void* __restrict__ outv,
                                                   unsigned char* __restrict__ outq,
                                                   int nrows) {
    const int tid = threadIdx.x;
    const int wave = tid >> 6;
    const int lane = tid & 63;
    const int l15 = lane & 15;
    const int lk = lane >> 4;  // k-group 0..3
    const int col0 = wave * 32;
    const int rbase = blockIdx.x * 64;

    bf16x8 breg[2][8];
#pragma unroll
    for (int c = 0; c < 2; ++c)
#pragma unroll
        for (int kc = 0; kc < 8; ++kc)
            breg[c][kc] = *(const bf16x8*)(Bt + (size_t)(col0 + c * 16 + l15) * 256 +
                                           kc * 32 + lk * 8);

    f32x4 acc[4][2];
#pragma unroll
    for (int rc = 0; rc < 4; ++rc) {
        acc[rc][0] = (f32x4)0.0f;
        acc[rc][1] = (f32x4)0.0f;
    }

#pragma unroll
    for (int rc = 0; rc < 4; ++rc) {
        const int arow = rbase + rc * 16 + l15;
        const bool ok = arow < nrows;
        bf16x8 a[8];
        if (ok) {
            if (A1BF16) {
                const unsigned short* A1 = (const unsigned short*)A1v;
#pragma unroll
                for (int kc = 0; kc < 4; ++kc) {
                    a[kc] = *(const bf16x8*)(A1 + (size_t)arow * NF + kc * 32 + lk * 8);
                    a[kc + 4] = *(const bf16x8*)(A2 + (size_t)arow * NF + kc * 32 + lk * 8);
                }
            } else {
                const float* A1 = (const float*)A1v;
#pragma unroll
                for (int kc = 0; kc < 4; ++kc) {
                    const float* p = A1 + (size_t)arow * NF + kc * 32 + lk * 8;
                    float4 u = *(const float4*)p;
                    float4 v = *(const float4*)(p + 4);
                    a[kc][0] = (short)f2bf(u.x); a[kc][1] = (short)f2bf(u.y);
                    a[kc][2] = (short)f2bf(u.z); a[kc][3] = (short)f2bf(u.w);
                    a[kc][4] = (short)f2bf(v.x); a[kc][5] = (short)f2bf(v.y);
                    a[kc][6] = (short)f2bf(v.z); a[kc][7] = (short)f2bf(v.w);
                    a[kc + 4] = *(const bf16x8*)(A2 + (size_t)arow * NF + kc * 32 + lk * 8);
                }
            }
        } else {
#pragma unroll
            for (int kc = 0; kc < 8; ++kc) a[kc] = (bf16x8)(short)0;
        }
#pragma unroll
        for (int kc = 0; kc < 8; ++kc) {
            acc[rc][0] = __builtin_amdgcn_mfma_f32_16x16x32_bf16(a[kc], breg[0][kc],
                                                                 acc[rc][0], 0, 0, 0);
            acc[rc][1] = __builtin_amdgcn_mfma_f32_16x16x32_bf16(a[kc], breg[1][kc],
                                                                 acc[rc][1], 0, 0, 0);
        }
    }

#pragma unroll
    for (int rc = 0; rc < 4; ++rc) {
#pragma unroll
        for (int r = 0; r < 4; ++r) {
            const int orow = rbase + rc * 16 + lk * 4 + r;
            if (orow >= nrows) continue;
#pragma unroll
            for (int c = 0; c < 2; ++c) {
                float v = acc[rc][c][r];
                if (RELU) v = fmaxf(v, 0.f);
                const int col = col0 + c * 16 + l15;
                if (OUTBF16)
                    ((unsigned short*)outv)[(size_t)orow * NF + col] = f2bf(v);
                else
                    ((float*)outv)[(size_t)orow * NF + col] = v;
                if (WRITEQ)
                    outq[(size_t)orow * NF + col] = f2fp8(v);
            }
        }
    }
}

extern "C" void kernel_launch(void* const* d_in, const int* in_sizes, int n_in,
                              void* d_out, int out_size, void* d_ws, size_t ws_size,
                              hipStream_t stream) {
    const float* x = (const float*)d_in[0];
    const float* W_in = (const float*)d_in[1];
    const float* W_out = (const float*)d_in[2];
    const int* src = (const int*)d_in[3];
    const int* dst = (const int*)d_in[4];

    const int n = in_sizes[0] / NF;  // 100000  (must stay < 2^24 for packed CSR)
    const int E = in_sizes[3];       // 1600000
    float* outp = (float*)d_out;

    const int NB = (n + 255) >> NBSHIFT;
    const int nchunks = (E + CHUNK - 1) / CHUNK;

    // workspace carve
    char* ws = (char*)d_ws;
    size_t off = 0;
    auto take = [&](size_t bytes) {
        void* p = ws + off;
        off = (off + bytes + 511) & ~(size_t)511;
        return p;
    };
    int* gbhist = (int*)take((size_t)NB * 4);
    int* bbase = (int*)take((size_t)(NB + 1) * 4);
    int* gcursor = (int*)take((size_t)NB * 4);
    int* offsets = (int*)take((size_t)(n + 1) * 4);
    float* invdeg = (float*)take((size_t)n * 4);
    unsigned short* BtIn = (unsigned short*)take(128 * 256 * 2);
    unsigned short* BtOut = (unsigned short*)take(128 * 256 * 2);
    unsigned* gpairs = (unsigned*)take((size_t)E * 4);
    int* esrc = (int*)take((size_t)E * 4);
    unsigned short* hb = (unsigned short*)take((size_t)n * NF * 2);
    unsigned short* neigh = (unsigned short*)take((size_t)n * NF * 2);
    // fp8 path extras: xb (bf16 x), xq (fp8 x), hq (fp8 h)
    size_t need_fp8 = off + (size_t)n * NF * 2 + 512 + (size_t)n * NF + 512 +
                      (size_t)n * NF + 512;
    bool use_fp8 = (ws_size >= need_fp8);
    unsigned short* xb = nullptr;
    unsigned char* xq = nullptr;
    unsigned char* hq = nullptr;
    if (use_fp8) {
        xb = (unsigned short*)take((size_t)n * NF * 2);
        xq = (unsigned char*)take((size_t)n * NF);
        hq = (unsigned char*)take((size_t)n * NF);
    }
    bool use_xb = use_fp8 || (ws_size >= off + (size_t)n * NF * 2);
    if (!use_fp8 && use_xb) xb = (unsigned short*)take((size_t)n * NF * 2);

    // ---- fused prep (bhist | buildBt | x->bf16+fp8) + CSR build ----
    hipMemsetAsync(gbhist, 0, (size_t)NB * 4, stream);
    const int cvtBlocks = use_fp8 ? (int)(((long long)n * NF / 8 + 255) / 256) : 0;
    k_prep<<<BH + BT + cvtBlocks, 256, 0, stream>>>(dst, E, NB, gbhist, x, xb, xq,
                                                    W_in, W_out, BtIn, BtOut);
    k_bscan<<<1, 256, 0, stream>>>(gbhist, bbase, gcursor, NB, E, offsets, n);
    k_bucket<<<nchunks, 256, 0, stream>>>(src, dst, gcursor, gpairs, E);
    k_bsort<<<NB, 256, 0, stream>>>(gpairs, bbase, offsets, invdeg, esrc, n);

    const int aggBlocks = (n + 3) / 4;
    const int gemmBlocks = (n + 63) / 64;

    if (use_fp8) {
        // ---- layer 0 ----
        k_agg_fp8<<<aggBlocks, 256, 0, stream>>>(xq, esrc, offsets, invdeg, neigh, n);
        k_gemm_mfma<true, true, true, true>
            <<<gemmBlocks, 256, 0, stream>>>(xb, neigh, BtIn, hb, hq, n);
        // ---- layer 1 ----
        k_agg_fp8<<<aggBlocks, 256, 0, stream>>>(hq, esrc, offsets, invdeg, neigh, n);
        k_gemm_mfma<false, true, false, false>
            <<<gemmBlocks, 256, 0, stream>>>(hb, neigh, BtOut, outp, nullptr, n);
    } else {
        // ---- fallback: bf16/fp32 path (round-8 behavior) ----
        k_agg_f32<<<aggBlocks, 256, 0, stream>>>(x, esrc, offsets, invdeg, neigh, n);
        k_gemm_mfma<true, false, true, false>
            <<<gemmBlocks, 256, 0, stream>>>(x, neigh, BtIn, hb, nullptr, n);
        k_agg_bf16<<<aggBlocks, 256, 0, stream>>>(hb, esrc, offsets, invdeg, neigh, n);
        k_gemm_mfma<false, true, false, false>
            <<<gemmBlocks, 256, 0, stream>>>(hb, neigh, BtOut, outp, nullptr, n);
    }
}

// Round 10
// 198.299 us; speedup vs baseline: 1.5585x; 1.2104x over previous
//
#include <hip/hip_runtime.h>

#define NF 128
#define NBSHIFT 8        // 256 nodes per bucket
#define NBMAX 512        // padded bucket count for scans
#define CHUNK 4096       // edges per multisplit chunk

typedef __attribute__((ext_vector_type(8))) short bf16x8;
typedef __attribute__((ext_vector_type(4))) float f32x4;
typedef __attribute__((ext_vector_type(2))) float f32x2;

__device__ __forceinline__ unsigned short f2bf(float f) {
    unsigned int u = __builtin_bit_cast(unsigned int, f);
    u = (u + 0x7fffu + ((u >> 16) & 1u)) >> 16;
    return (unsigned short)u;
}
__device__ __forceinline__ float bflo(unsigned int u) {
    return __builtin_bit_cast(float, u << 16);
}
__device__ __forceinline__ float bfhi(unsigned int u) {
    return __builtin_bit_cast(float, u & 0xffff0000u);
}
__device__ __forceinline__ unsigned char f2fp8(float v) {
    return (unsigned char)(__builtin_amdgcn_cvt_pk_fp8_f32(v, v, 0, false) & 0xff);
}

// ================= fused prep: bhist | buildBt | cvt(x -> bf16 + fp8) =================
#define BH 256
#define BT 256
__global__ __launch_bounds__(256) void k_prep(const int* __restrict__ dst, int E, int NB,
                                              int* __restrict__ gbhist,
                                              const float* __restrict__ x,
                                              unsigned short* __restrict__ xb,
                                              unsigned char* __restrict__ xq,
                                              const float* __restrict__ Win,
                                              const float* __restrict__ Wout,
                                              unsigned short* __restrict__ BtIn,
                                              unsigned short* __restrict__ BtOut) {
    __shared__ int lh[NBMAX];
    const int bb = blockIdx.x;
    const int t = threadIdx.x;
    if (bb < BH) {
        for (int k = t; k < NBMAX; k += 256) lh[k] = 0;
        __syncthreads();
        for (int i = bb * 256 + t; i < E; i += BH * 256)
            atomicAdd(&lh[((unsigned)dst[i]) >> NBSHIFT], 1);
        __syncthreads();
        for (int k = t; k < NB; k += 256)
            if (lh[k]) atomicAdd(&gbhist[k], lh[k]);
    } else if (bb < BH + BT) {
        int b2 = bb - BH;
        const float* W = (b2 < 128) ? Win : Wout;
        unsigned short* Bt = (b2 < 128) ? BtIn : BtOut;
        int idx = (b2 & 127) * 256 + t;
        int c = idx >> 8;
        int k = idx & 255;
        int p = k >> 7, kk = k & 127;
        Bt[idx] = f2bf(W[((size_t)p * NF + kk) * NF + c]);
    } else {
        long long i = (long long)(bb - BH - BT) * 256 + t;
        const float4 a = *reinterpret_cast<const float4*>(x + i * 8);
        const float4 b = *reinterpret_cast<const float4*>(x + i * 8 + 4);
        union { unsigned short s[8]; uint4 u; } o;
        o.s[0] = f2bf(a.x); o.s[1] = f2bf(a.y); o.s[2] = f2bf(a.z); o.s[3] = f2bf(a.w);
        o.s[4] = f2bf(b.x); o.s[5] = f2bf(b.y); o.s[6] = f2bf(b.z); o.s[7] = f2bf(b.w);
        *reinterpret_cast<uint4*>(xb + i * 8) = o.u;
        int lo = __builtin_amdgcn_cvt_pk_fp8_f32(a.x, a.y, 0, false);
        lo = __builtin_amdgcn_cvt_pk_fp8_f32(a.z, a.w, lo, true);
        int hi = __builtin_amdgcn_cvt_pk_fp8_f32(b.x, b.y, 0, false);
        hi = __builtin_amdgcn_cvt_pk_fp8_f32(b.z, b.w, hi, true);
        uint2 oq; oq.x = (unsigned)lo; oq.y = (unsigned)hi;
        *reinterpret_cast<uint2*>(xq + i * 8) = oq;
    }
}

// ================= CSR build =================

__global__ __launch_bounds__(256) void k_bscan(const int* __restrict__ gbhist,
                                               int* __restrict__ bbase, int* __restrict__ gcursor,
                                               int NB, int E, int* __restrict__ offsets, int n) {
    __shared__ int sA[NBMAX], sB[NBMAX];
    int t = threadIdx.x;
    for (int k = t; k < NBMAX; k += 256) sA[k] = (k < NB) ? gbhist[k] : 0;
    __syncthreads();
    int* pin = sA;
    int* pout = sB;
    for (int off = 1; off < NBMAX; off <<= 1) {
        for (int k = t; k < NBMAX; k += 256) pout[k] = pin[k] + (k >= off ? pin[k - off] : 0);
        __syncthreads();
        int* tmp = pin; pin = pout; pout = tmp;
    }
    for (int k = t; k < NB; k += 256) {
        int excl = pin[k] - gbhist[k];
        bbase[k] = excl;
        gcursor[k] = excl;
    }
    if (t == 0) {
        bbase[NB] = E;
        offsets[n] = E;
    }
}

// chunked multisplit; edge packed 32-bit: (dst&255)<<24 | src  (needs n < 2^24)
__global__ __launch_bounds__(256) void k_bucket(const int* __restrict__ src,
                                                const int* __restrict__ dst,
                                                int* __restrict__ gcursor,
                                                unsigned* __restrict__ gpairs, int E) {
    __shared__ int lhist[NBMAX], lbase[NBMAX], lcur[NBMAX], gb[NBMAX];
    __shared__ int sA[NBMAX], sB[NBMAX];
    __shared__ unsigned stage[CHUNK];
    __shared__ unsigned short stage_b[CHUNK];
    const int t = threadIdx.x;
    const int c0 = blockIdx.x * CHUNK;
    const int cc = min(CHUNK, E - c0);

    for (int k = t; k < NBMAX; k += 256) lhist[k] = 0;
    __syncthreads();

    int ls[16], ld[16];
#pragma unroll
    for (int j = 0; j < 16; ++j) {
        int i = t + j * 256;
        ls[j] = 0; ld[j] = 0;
        if (i < cc) {
            ls[j] = src[c0 + i];
            ld[j] = dst[c0 + i];
            atomicAdd(&lhist[((unsigned)ld[j]) >> NBSHIFT], 1);
        }
    }
    __syncthreads();
    for (int k = t; k < NBMAX; k += 256) sA[k] = lhist[k];
    __syncthreads();
    int* pin = sA;
    int* pout = sB;
    for (int off = 1; off < NBMAX; off <<= 1) {
        for (int k = t; k < NBMAX; k += 256) pout[k] = pin[k] + (k >= off ? pin[k - off] : 0);
        __syncthreads();
        int* tmp = pin; pin = pout; pout = tmp;
    }
    for (int k = t; k < NBMAX; k += 256) {
        int excl = pin[k] - lhist[k];
        lbase[k] = excl;
        lcur[k] = excl;
        int cnt = lhist[k];
        if (cnt > 0) gb[k] = atomicAdd(&gcursor[k], cnt);
    }
    __syncthreads();
#pragma unroll
    for (int j = 0; j < 16; ++j) {
        int i = t + j * 256;
        if (i < cc) {
            int b = ((unsigned)ld[j]) >> NBSHIFT;
            int pos = atomicAdd(&lcur[b], 1);
            stage[pos] = (((unsigned)ld[j] & 255u) << 24) | (unsigned)ls[j];
            stage_b[pos] = (unsigned short)b;
        }
    }
    __syncthreads();
    for (int idx = t; idx < cc; idx += 256) {
        unsigned p = stage[idx];
        int b = stage_b[idx];
        gpairs[gb[b] + (idx - lbase[b])] = p;
    }
}

// per-bucket: per-node hist + scan -> offsets/invdeg, scatter esrc within bucket region
__global__ __launch_bounds__(256) void k_bsort(const unsigned* __restrict__ gpairs,
                                               const int* __restrict__ bbase,
                                               int* __restrict__ offsets,
                                               float* __restrict__ invdeg,
                                               int* __restrict__ esrc, int n) {
    __shared__ int lcnt[256], lcur[256], sA[256], sB[256];
    const int b = blockIdx.x;
    const int t = threadIdx.x;
    const int base = bbase[b];
    const int c = bbase[b + 1] - base;
    const int n0 = b << NBSHIFT;

    lcnt[t] = 0;
    __syncthreads();
    for (int i = t; i < c; i += 256) {
        int node = (int)(gpairs[base + i] >> 24);
        atomicAdd(&lcnt[node], 1);
    }
    __syncthreads();
    sA[t] = lcnt[t];
    __syncthreads();
    int* pin = sA;
    int* pout = sB;
    for (int off = 1; off < 256; off <<= 1) {
        pout[t] = pin[t] + (t >= off ? pin[t - off] : 0);
        __syncthreads();
        int* tmp = pin; pin = pout; pout = tmp;
    }
    int excl = pin[t] - lcnt[t];
    lcur[t] = excl;
    int node_g = n0 + t;
    if (node_g < n) {
        offsets[node_g] = base + excl;
        invdeg[node_g] = 1.0f / (float)max(lcnt[t], 1);
    }
    __syncthreads();
    for (int i = t; i < c; i += 256) {
        unsigned p = gpairs[base + i];
        int node = (int)(p >> 24);
        int pos = atomicAdd(&lcur[node], 1);
        esrc[base + pos] = (int)(p & 0x00ffffffu);
    }
}

// ================= gather aggregation (fp8 source, 4 edges/load) =================
__global__ __launch_bounds__(256) void k_agg_fp8(const unsigned char* __restrict__ feat,
                                                 const int* __restrict__ esrc,
                                                 const int* __restrict__ offsets,
                                                 const float* __restrict__ invdeg,
                                                 unsigned short* __restrict__ neigh, int n) {
    int wid0 = (int)(((long long)blockIdx.x * blockDim.x + threadIdx.x) >> 6);
    const int wid = __builtin_amdgcn_readfirstlane(wid0);
    if (wid >= n) return;
    const int lane = threadIdx.x & 63;
    const int g = lane >> 4;        // edge slot within quad
    const int q = lane & 15;        // column group: fp8 bytes [q*8, q*8+8)
    const unsigned qoff = (unsigned)q * 8u;
    const unsigned char* fb = feat;

    const int beg = offsets[wid];
    const int end = offsets[wid + 1];
    f32x2 c01 = {0.f, 0.f}, c23 = {0.f, 0.f}, c45 = {0.f, 0.f}, c67 = {0.f, 0.f};

    int i = beg;
    for (; i + 16 <= end; i += 16) {
        int e[16];
#pragma unroll
        for (int j = 0; j < 16; ++j) e[j] = esrc[i + j];
#pragma unroll
        for (int u = 0; u < 4; ++u) {
            int es = (g & 2) ? ((g & 1) ? e[u * 4 + 3] : e[u * 4 + 2])
                             : ((g & 1) ? e[u * 4 + 1] : e[u * 4 + 0]);
            uint2 v = *(const uint2*)(fb + (unsigned)es * 128u + qoff);
            c01 += __builtin_amdgcn_cvt_pk_f32_fp8((int)v.x, false);
            c23 += __builtin_amdgcn_cvt_pk_f32_fp8((int)v.x, true);
            c45 += __builtin_amdgcn_cvt_pk_f32_fp8((int)v.y, false);
            c67 += __builtin_amdgcn_cvt_pk_f32_fp8((int)v.y, true);
        }
    }
    for (; i + 4 <= end; i += 4) {
        int e0 = esrc[i + 0], e1 = esrc[i + 1], e2 = esrc[i + 2], e3 = esrc[i + 3];
        int es = (g & 2) ? ((g & 1) ? e3 : e2) : ((g & 1) ? e1 : e0);
        uint2 v = *(const uint2*)(fb + (unsigned)es * 128u + qoff);
        c01 += __builtin_amdgcn_cvt_pk_f32_fp8((int)v.x, false);
        c23 += __builtin_amdgcn_cvt_pk_f32_fp8((int)v.x, true);
        c45 += __builtin_amdgcn_cvt_pk_f32_fp8((int)v.y, false);
        c67 += __builtin_amdgcn_cvt_pk_f32_fp8((int)v.y, true);
    }
    if (i < end) {
        int r = end - i;  // 1..3
        if (g < r) {
            int es = esrc[i + g];
            uint2 v = *(const uint2*)(fb + (unsigned)es * 128u + qoff);
            c01 += __builtin_amdgcn_cvt_pk_f32_fp8((int)v.x, false);
            c23 += __builtin_amdgcn_cvt_pk_f32_fp8((int)v.x, true);
            c45 += __builtin_amdgcn_cvt_pk_f32_fp8((int)v.y, false);
            c67 += __builtin_amdgcn_cvt_pk_f32_fp8((int)v.y, true);
        }
    }
    float a0 = c01.x, a1 = c01.y, a2 = c23.x, a3 = c23.y;
    float a4 = c45.x, a5 = c45.y, a6 = c67.x, a7 = c67.y;
    a0 += __shfl_xor(a0, 16); a1 += __shfl_xor(a1, 16);
    a2 += __shfl_xor(a2, 16); a3 += __shfl_xor(a3, 16);
    a4 += __shfl_xor(a4, 16); a5 += __shfl_xor(a5, 16);
    a6 += __shfl_xor(a6, 16); a7 += __shfl_xor(a7, 16);
    a0 += __shfl_xor(a0, 32); a1 += __shfl_xor(a1, 32);
    a2 += __shfl_xor(a2, 32); a3 += __shfl_xor(a3, 32);
    a4 += __shfl_xor(a4, 32); a5 += __shfl_xor(a5, 32);
    a6 += __shfl_xor(a6, 32); a7 += __shfl_xor(a7, 32);

    const float sc = invdeg[wid];
    a0 *= sc; a1 *= sc; a2 *= sc; a3 *= sc;
    a4 *= sc; a5 *= sc; a6 *= sc; a7 *= sc;
    unsigned p0, p1, p2, p3;
    asm("v_cvt_pk_bf16_f32 %0, %1, %2" : "=v"(p0) : "v"(a0), "v"(a1));
    asm("v_cvt_pk_bf16_f32 %0, %1, %2" : "=v"(p1) : "v"(a2), "v"(a3));
    asm("v_cvt_pk_bf16_f32 %0, %1, %2" : "=v"(p2) : "v"(a4), "v"(a5));
    asm("v_cvt_pk_bf16_f32 %0, %1, %2" : "=v"(p3) : "v"(a6), "v"(a7));
    if (g == 0) {
        uint4 o; o.x = p0; o.y = p1; o.z = p2; o.w = p3;
        *(uint4*)((char*)neigh + (size_t)wid * 256 + (unsigned)q * 16u) = o;
    }
}

// fallback bf16-source aggregate
__global__ __launch_bounds__(256) void k_agg_bf16(const unsigned short* __restrict__ feat,
                                                  const int* __restrict__ esrc,
                                                  const int* __restrict__ offsets,
                                                  const float* __restrict__ invdeg,
                                                  unsigned short* __restrict__ neigh, int n) {
    int wid0 = (int)(((long long)blockIdx.x * blockDim.x + threadIdx.x) >> 6);
    const int wid = __builtin_amdgcn_readfirstlane(wid0);
    if (wid >= n) return;
    const int lane = threadIdx.x & 63;
    const int g = lane >> 4;
    const int q = lane & 15;
    const unsigned qoff = (unsigned)q * 16u;
    const char* fb = (const char*)feat;
    const int beg = offsets[wid];
    const int end = offsets[wid + 1];
    float a0 = 0.f, a1 = 0.f, a2 = 0.f, a3 = 0.f, a4 = 0.f, a5 = 0.f, a6 = 0.f, a7 = 0.f;
    int i = beg;
    for (; i + 4 <= end; i += 4) {
        int e0 = esrc[i + 0], e1 = esrc[i + 1], e2 = esrc[i + 2], e3 = esrc[i + 3];
        int es = (g & 2) ? ((g & 1) ? e3 : e2) : ((g & 1) ? e1 : e0);
        uint4 v = *(const uint4*)(fb + (unsigned)es * 256u + qoff);
        a0 += bflo(v.x); a1 += bfhi(v.x);
        a2 += bflo(v.y); a3 += bfhi(v.y);
        a4 += bflo(v.z); a5 += bfhi(v.z);
        a6 += bflo(v.w); a7 += bfhi(v.w);
    }
    if (i < end) {
        int r = end - i;
        if (g < r) {
            int es = esrc[i + g];
            uint4 v = *(const uint4*)(fb + (unsigned)es * 256u + qoff);
            a0 += bflo(v.x); a1 += bfhi(v.x);
            a2 += bflo(v.y); a3 += bfhi(v.y);
            a4 += bflo(v.z); a5 += bfhi(v.z);
            a6 += bflo(v.w); a7 += bfhi(v.w);
        }
    }
    a0 += __shfl_xor(a0, 16); a1 += __shfl_xor(a1, 16);
    a2 += __shfl_xor(a2, 16); a3 += __shfl_xor(a3, 16);
    a4 += __shfl_xor(a4, 16); a5 += __shfl_xor(a5, 16);
    a6 += __shfl_xor(a6, 16); a7 += __shfl_xor(a7, 16);
    a0 += __shfl_xor(a0, 32); a1 += __shfl_xor(a1, 32);
    a2 += __shfl_xor(a2, 32); a3 += __shfl_xor(a3, 32);
    a4 += __shfl_xor(a4, 32); a5 += __shfl_xor(a5, 32);
    a6 += __shfl_xor(a6, 32); a7 += __shfl_xor(a7, 32);
    const float sc = invdeg[wid];
    a0 *= sc; a1 *= sc; a2 *= sc; a3 *= sc;
    a4 *= sc; a5 *= sc; a6 *= sc; a7 *= sc;
    unsigned p0, p1, p2, p3;
    asm("v_cvt_pk_bf16_f32 %0, %1, %2" : "=v"(p0) : "v"(a0), "v"(a1));
    asm("v_cvt_pk_bf16_f32 %0, %1, %2" : "=v"(p1) : "v"(a2), "v"(a3));
    asm("v_cvt_pk_bf16_f32 %0, %1, %2" : "=v"(p2) : "v"(a4), "v"(a5));
    asm("v_cvt_pk_bf16_f32 %0, %1, %2" : "=v"(p3) : "v"(a6), "v"(a7));
    if (g == 0) {
        uint4 o; o.x = p0; o.y = p1; o.z = p2; o.w = p3;
        *(uint4*)((char*)neigh + (size_t)wid * 256 + qoff) = o;
    }
}

// fallback fp32-source aggregate
__global__ __launch_bounds__(256) void k_agg_f32(const float* __restrict__ feat,
                                                 const int* __restrict__ esrc,
                                                 const int* __restrict__ offsets,
                                                 const float* __restrict__ invdeg,
                                                 unsigned short* __restrict__ neigh, int n) {
    int wid0 = (int)(((long long)blockIdx.x * blockDim.x + threadIdx.x) >> 6);
    const int wid = __builtin_amdgcn_readfirstlane(wid0);
    if (wid >= n) return;
    int lane = threadIdx.x & 63;
    int beg = offsets[wid], end = offsets[wid + 1];
    float a0 = 0.f, a1 = 0.f;
    for (int i = beg; i < end; ++i) {
        int s0 = esrc[i];
        float2 v0 = *(const float2*)(feat + (size_t)s0 * NF + lane * 2);
        a0 += v0.x; a1 += v0.y;
    }
    float sc = invdeg[wid];
    unsigned pk;
    float ca = a0 * sc, cb = a1 * sc;
    asm("v_cvt_pk_bf16_f32 %0, %1, %2" : "=v"(pk) : "v"(ca), "v"(cb));
    *(unsigned*)(neigh + (size_t)wid * NF + lane * 2) = pk;
}

// ================= MFMA GEMM, LDS-staged (fp8 path): out = act(A1@W0 + A2@W1) ========
// Block: 256 thr = 4 waves, 64 rows x 128 cols, K=256 (A1 | A2).
// A staged into LDS via global_load_lds w=16 with XOR-swizzled SOURCE (linear dest);
// ds_read_b128 fragments use the matching chunk^(row&7) swizzle (<=2-way bank alias).
// B panel (32 cols x 256 k) register-stationary per wave. Epilogue re-packed through
// LDS -> coalesced dwordx4 stores (bf16 / fp8 / f32).
template <bool RELU, bool OUTBF16, bool WRITEQ>
__global__ __launch_bounds__(256) void k_gemm_lds(const unsigned short* __restrict__ A1,
                                                  const unsigned short* __restrict__ A2,
                                                  const unsigned short* __restrict__ Bt,
                                                  void* __restrict__ outv,
                                                  unsigned char* __restrict__ outq,
                                                  int nrows) {
    __shared__ __align__(16) unsigned char sm[32768];  // [2][64 rows][128 k] bf16
    const int tid = threadIdx.x;
    const int w = tid >> 6;
    const int lane = tid & 63;
    const int l15 = lane & 15;
    const int lk = lane >> 4;  // 0..3
    const int col0 = w * 32;
    const int rbase = blockIdx.x * 64;

    // ---- async stage: wave w stages rows [w*16, w*16+16) of each half ----
#pragma unroll
    for (int h = 0; h < 2; ++h) {
        const unsigned short* Ah = h ? A2 : A1;
#pragma unroll
        for (int j = 0; j < 4; ++j) {
            const int r = w * 16 + j * 4 + lk;           // row in tile this lane feeds
            const int garow = min(rbase + r, nrows - 1);
            const int cch = l15 ^ (r & 7);               // swizzled source chunk
            const unsigned short* srcp = Ah + (size_t)garow * NF + cch * 8;
            unsigned char* ldst = &sm[h * 16384 + (w * 16 + j * 4) * 256];
            __builtin_amdgcn_global_load_lds(
                (const __attribute__((address_space(1))) void*)srcp,
                (__attribute__((address_space(3))) void*)ldst, 16, 0, 0);
        }
    }

    // ---- B panel preload (register-stationary, L2-hot) ----
    bf16x8 breg[2][8];
#pragma unroll
    for (int c = 0; c < 2; ++c)
#pragma unroll
        for (int kc = 0; kc < 8; ++kc)
            breg[c][kc] = *(const bf16x8*)(Bt + (size_t)(col0 + c * 16 + l15) * 256 +
                                           kc * 32 + lk * 8);

    f32x4 acc[4][2];
#pragma unroll
    for (int rc = 0; rc < 4; ++rc) {
        acc[rc][0] = (f32x4)0.0f;
        acc[rc][1] = (f32x4)0.0f;
    }

    __syncthreads();  // drains vmcnt (incl. global_load_lds) before LDS reads

    // ---- MFMA main: 32 ds_read_b128 + 64 MFMA per wave ----
#pragma unroll
    for (int rc = 0; rc < 4; ++rc) {
        const int row = rc * 16 + l15;
#pragma unroll
        for (int kc = 0; kc < 8; ++kc) {
            const int half = kc >> 2;
            const int kk = kc & 3;
            const int chunk = (kk * 4 + lk) ^ (row & 7);
            const bf16x8 a = *(const bf16x8*)&sm[half * 16384 + row * 256 + chunk * 16];
            acc[rc][0] = __builtin_amdgcn_mfma_f32_16x16x32_bf16(a, breg[0][kc],
                                                                 acc[rc][0], 0, 0, 0);
            acc[rc][1] = __builtin_amdgcn_mfma_f32_16x16x32_bf16(a, breg[1][kc],
                                                                 acc[rc][1], 0, 0, 0);
        }
    }

    __syncthreads();  // all fragment reads done; sm is reusable

    // ---- epilogue through LDS -> coalesced stores ----
    if (OUTBF16) {
        unsigned short* smb = (unsigned short*)sm;          // 16KB bf16 tile
        unsigned char* smq = sm + 16384;                    // 8KB fp8 tile
#pragma unroll
        for (int rc = 0; rc < 4; ++rc)
#pragma unroll
            for (int r = 0; r < 4; ++r) {
                const int row = rc * 16 + lk * 4 + r;
#pragma unroll
                for (int c = 0; c < 2; ++c) {
                    float v = acc[rc][c][r];
                    if (RELU) v = fmaxf(v, 0.f);
                    const int col = col0 + c * 16 + l15;
                    smb[row * NF + col] = f2bf(v);
                    if (WRITEQ) smq[row * NF + col] = f2fp8(v);
                }
            }
        __syncthreads();
#pragma unroll
        for (int it = 0; it < 4; ++it) {
            const int off = (tid + it * 256) * 16;          // byte off in 16KB bf16 tile
            if (rbase + (off >> 8) < nrows)
                *(uint4*)((char*)outv + (size_t)rbase * 256 + off) =
                    *(const uint4*)&sm[off];
        }
        if (WRITEQ) {
#pragma unroll
            for (int it = 0; it < 2; ++it) {
                const int off = (tid + it * 256) * 16;      // byte off in 8KB fp8 tile
                if (rbase + (off >> 7) < nrows)
                    *(uint4*)(outq + (size_t)rbase * 128 + off) =
                        *(const uint4*)&sm[16384 + off];
            }
        }
    } else {
        float* smf = (float*)sm;                            // 32KB f32 tile
#pragma unroll
        for (int rc = 0; rc < 4; ++rc)
#pragma unroll
            for (int r = 0; r < 4; ++r) {
                const int row = rc * 16 + lk * 4 + r;
#pragma unroll
                for (int c = 0; c < 2; ++c) {
                    float v = acc[rc][c][r];
                    if (RELU) v = fmaxf(v, 0.f);
                    smf[row * NF + col0 + c * 16 + l15] = v;
                }
            }
        __syncthreads();
#pragma unroll
        for (int it = 0; it < 8; ++it) {
            const int off = (tid + it * 256) * 16;          // byte off in 32KB f32 tile
            if (rbase + (off >> 9) < nrows)
                *(uint4*)((char*)outv + (size_t)rbase * 512 + off) =
                    *(const uint4*)&sm[off];
        }
    }
}

// ================= fallback GEMM (non-fp8 path), B-stationary from global ==========
template <bool RELU, bool A1BF16, bool OUTBF16>
__global__ __launch_bounds__(256) void k_gemm_mfma(const void* __restrict__ A1v,
                                                   const unsigned short* __restrict__ A2,
                                                   const unsigned short* __restrict__ Bt,
                                                   void* __restrict__ outv, int nrows) {
    const int tid = threadIdx.x;
    const int wave = tid >> 6;
    const int lane = tid & 63;
    const int l15 = lane & 15;
    const int lk = lane >> 4;
    const int col0 = wave * 32;
    const int rbase = blockIdx.x * 64;

    bf16x8 breg[2][8];
#pragma unroll
    for (int c = 0; c < 2; ++c)
#pragma unroll
        for (int kc = 0; kc < 8; ++kc)
            breg[c][kc] = *(const bf16x8*)(Bt + (size_t)(col0 + c * 16 + l15) * 256 +
                                           kc * 32 + lk * 8);

    f32x4 acc[4][2];
#pragma unroll
    for (int rc = 0; rc < 4; ++rc) {
        acc[rc][0] = (f32x4)0.0f;
        acc[rc][1] = (f32x4)0.0f;
    }

#pragma unroll
    for (int rc = 0; rc < 4; ++rc) {
        const int arow = rbase + rc * 16 + l15;
        const bool ok = arow < nrows;
        bf16x8 a[8];
        if (ok) {
            if (A1BF16) {
                const unsigned short* A1 = (const unsigned short*)A1v;
#pragma unroll
                for (int kc = 0; kc < 4; ++kc) {
                    a[kc] = *(const bf16x8*)(A1 + (size_t)arow * NF + kc * 32 + lk * 8);
                    a[kc + 4] = *(const bf16x8*)(A2 + (size_t)arow * NF + kc * 32 + lk * 8);
                }
            } else {
                const float* A1 = (const float*)A1v;
#pragma unroll
                for (int kc = 0; kc < 4; ++kc) {
                    const float* p = A1 + (size_t)arow * NF + kc * 32 + lk * 8;
                    float4 u = *(const float4*)p;
                    float4 v = *(const float4*)(p + 4);
                    a[kc][0] = (short)f2bf(u.x); a[kc][1] = (short)f2bf(u.y);
                    a[kc][2] = (short)f2bf(u.z); a[kc][3] = (short)f2bf(u.w);
                    a[kc][4] = (short)f2bf(v.x); a[kc][5] = (short)f2bf(v.y);
                    a[kc][6] = (short)f2bf(v.z); a[kc][7] = (short)f2bf(v.w);
                    a[kc + 4] = *(const bf16x8*)(A2 + (size_t)arow * NF + kc * 32 + lk * 8);
                }
            }
        } else {
#pragma unroll
            for (int kc = 0; kc < 8; ++kc) a[kc] = (bf16x8)(short)0;
        }
#pragma unroll
        for (int kc = 0; kc < 8; ++kc) {
            acc[rc][0] = __builtin_amdgcn_mfma_f32_16x16x32_bf16(a[kc], breg[0][kc],
                                                                 acc[rc][0], 0, 0, 0);
            acc[rc][1] = __builtin_amdgcn_mfma_f32_16x16x32_bf16(a[kc], breg[1][kc],
                                                                 acc[rc][1], 0, 0, 0);
        }
    }

#pragma unroll
    for (int rc = 0; rc < 4; ++rc) {
#pragma unroll
        for (int r = 0; r < 4; ++r) {
            const int orow = rbase + rc * 16 + lk * 4 + r;
            if (orow >= nrows) continue;
#pragma unroll
            for (int c = 0; c < 2; ++c) {
                float v = acc[rc][c][r];
                if (RELU) v = fmaxf(v, 0.f);
                const int col = col0 + c * 16 + l15;
                if (OUTBF16)
                    ((unsigned short*)outv)[(size_t)orow * NF + col] = f2bf(v);
                else
                    ((float*)outv)[(size_t)orow * NF + col] = v;
            }
        }
    }
}

extern "C" void kernel_launch(void* const* d_in, const int* in_sizes, int n_in,
                              void* d_out, int out_size, void* d_ws, size_t ws_size,
                              hipStream_t stream) {
    const float* x = (const float*)d_in[0];
    const float* W_in = (const float*)d_in[1];
    const float* W_out = (const float*)d_in[2];
    const int* src = (const int*)d_in[3];
    const int* dst = (const int*)d_in[4];

    const int n = in_sizes[0] / NF;  // 100000  (must stay < 2^24 for packed CSR)
    const int E = in_sizes[3];       // 1600000
    float* outp = (float*)d_out;

    const int NB = (n + 255) >> NBSHIFT;
    const int nchunks = (E + CHUNK - 1) / CHUNK;

    // workspace carve
    char* ws = (char*)d_ws;
    size_t off = 0;
    auto take = [&](size_t bytes) {
        void* p = ws + off;
        off = (off + bytes + 511) & ~(size_t)511;
        return p;
    };
    int* gbhist = (int*)take((size_t)NB * 4);
    int* bbase = (int*)take((size_t)(NB + 1) * 4);
    int* gcursor = (int*)take((size_t)NB * 4);
    int* offsets = (int*)take((size_t)(n + 1) * 4);
    float* invdeg = (float*)take((size_t)n * 4);
    unsigned short* BtIn = (unsigned short*)take(128 * 256 * 2);
    unsigned short* BtOut = (unsigned short*)take(128 * 256 * 2);
    unsigned* gpairs = (unsigned*)take((size_t)E * 4);
    int* esrc = (int*)take((size_t)E * 4);
    unsigned short* hb = (unsigned short*)take((size_t)n * NF * 2);
    unsigned short* neigh = (unsigned short*)take((size_t)n * NF * 2);
    size_t need_fp8 = off + (size_t)n * NF * 2 + 512 + (size_t)n * NF + 512 +
                      (size_t)n * NF + 512;
    bool use_fp8 = (ws_size >= need_fp8);
    unsigned short* xb = nullptr;
    unsigned char* xq = nullptr;
    unsigned char* hq = nullptr;
    if (use_fp8) {
        xb = (unsigned short*)take((size_t)n * NF * 2);
        xq = (unsigned char*)take((size_t)n * NF);
        hq = (unsigned char*)take((size_t)n * NF);
    }
    bool use_xb = use_fp8 || (ws_size >= off + (size_t)n * NF * 2);
    if (!use_fp8 && use_xb) xb = (unsigned short*)take((size_t)n * NF * 2);

    // ---- fused prep (bhist | buildBt | x->bf16+fp8) + CSR build ----
    hipMemsetAsync(gbhist, 0, (size_t)NB * 4, stream);
    const int cvtBlocks = use_fp8 ? (int)(((long long)n * NF / 8 + 255) / 256) : 0;
    k_prep<<<BH + BT + cvtBlocks, 256, 0, stream>>>(dst, E, NB, gbhist, x, xb, xq,
                                                    W_in, W_out, BtIn, BtOut);
    k_bscan<<<1, 256, 0, stream>>>(gbhist, bbase, gcursor, NB, E, offsets, n);
    k_bucket<<<nchunks, 256, 0, stream>>>(src, dst, gcursor, gpairs, E);
    k_bsort<<<NB, 256, 0, stream>>>(gpairs, bbase, offsets, invdeg, esrc, n);

    const int aggBlocks = (n + 3) / 4;
    const int gemmBlocks = (n + 63) / 64;

    if (use_fp8) {
        // ---- layer 0 ----
        k_agg_fp8<<<aggBlocks, 256, 0, stream>>>(xq, esrc, offsets, invdeg, neigh, n);
        k_gemm_lds<true, true, true>
            <<<gemmBlocks, 256, 0, stream>>>(xb, neigh, BtIn, hb, hq, n);
        // ---- layer 1 ----
        k_agg_fp8<<<aggBlocks, 256, 0, stream>>>(hq, esrc, offsets, invdeg, neigh, n);
        k_gemm_lds<false, false, false>
            <<<gemmBlocks, 256, 0, stream>>>(hb, neigh, BtOut, outp, nullptr, n);
    } else {
        // ---- fallback path ----
        k_agg_f32<<<aggBlocks, 256, 0, stream>>>(x, esrc, offsets, invdeg, neigh, n);
        k_gemm_mfma<true, false, true>
            <<<gemmBlocks, 256, 0, stream>>>(x, neigh, BtIn, hb, n);
        k_agg_bf16<<<aggBlocks, 256, 0, stream>>>(hb, esrc, offsets, invdeg, neigh, n);
        k_gemm_mfma<false, true, false>
            <<<gemmBlocks, 256, 0, stream>>>(hb, neigh, BtOut, outp, n);
    }
}